// Round 1
// baseline (15166.002 us; speedup 1.0000x reference)
//
#include <hip/hip_runtime.h>
#include <math.h>

// ---- problem constants ----
constexpr int SEQ = 2048;
constexpr int DIM = 1024;
constexpr int NH  = 16;
constexpr int HD  = 64;
constexpr int FF  = 4096;
constexpr int NL  = 12;
constexpr int VOC = 1400;

typedef __bf16 bf16_t;
typedef __bf16 bf16x8 __attribute__((ext_vector_type(8)));
typedef float  f32x4  __attribute__((ext_vector_type(4)));

// ---------------- embedding gather ----------------
__global__ __launch_bounds__(256) void k_embed(const int* __restrict__ ids,
                                               const float* __restrict__ emb,
                                               float* __restrict__ x) {
  int s = blockIdx.x;
  int d = threadIdx.x * 4;
  const float4 v = *(const float4*)&emb[(size_t)ids[s] * DIM + d];
  *(float4*)&x[(size_t)s * DIM + d] = v;
}

// ---------------- layernorm (f32 in -> bf16 out), 1 wave per row ----------------
__global__ __launch_bounds__(64) void k_ln(const float* __restrict__ x,
                                           const float* __restrict__ sc,
                                           const float* __restrict__ bi,
                                           bf16_t* __restrict__ out) {
  int s = blockIdx.x;
  int l = threadIdx.x;
  const float* xr = x + (size_t)s * DIM;
  float4 v[4];
  float sum = 0.f, sq = 0.f;
#pragma unroll
  for (int i = 0; i < 4; ++i) {
    v[i] = *(const float4*)&xr[i * 256 + l * 4];
#pragma unroll
    for (int j = 0; j < 4; ++j) { sum += v[i][j]; sq += v[i][j] * v[i][j]; }
  }
#pragma unroll
  for (int d = 1; d < 64; d <<= 1) {
    sum += __shfl_xor(sum, d);
    sq  += __shfl_xor(sq, d);
  }
  float mean = sum * (1.f / DIM);
  float var  = sq * (1.f / DIM) - mean * mean;
  float inv  = rsqrtf(var + 1e-5f);
#pragma unroll
  for (int i = 0; i < 4; ++i) {
    int off = i * 256 + l * 4;
    float4 scv = *(const float4*)&sc[off];
    float4 biv = *(const float4*)&bi[off];
#pragma unroll
    for (int j = 0; j < 4; ++j) {
      float o = (v[i][j] - mean) * inv * scv[j] + biv[j];
      out[(size_t)s * DIM + off + j] = (bf16_t)o;
    }
  }
}

// ---------------- GEMM: C[M,N] = A[M,K](bf16) * B[K,N](f32 weights) ----------------
// OUTMODE 0: store f32   1: store bf16   2: f32 +=
template <int OUTMODE>
__global__ __launch_bounds__(256) void k_gemm(const bf16_t* __restrict__ A,
                                              const float* __restrict__ B,
                                              float* __restrict__ Cf,
                                              bf16_t* __restrict__ Cb,
                                              int M, int N, int K) {
  __shared__ bf16_t As[64][40];   // padded: row stride 80B, 16B aligned
  __shared__ bf16_t Bs[64][40];   // transposed: Bs[n][k]
  const int m0 = blockIdx.y * 64;
  const int n0 = blockIdx.x * 64;
  const int t = threadIdx.x;
  const int w = t >> 6;
  const int l = t & 63;
  const int h = l >> 4;
  const int r16 = l & 15;
  const int wr = (w >> 1) * 32;
  const int wc = (w & 1) * 32;

  f32x4 acc[2][2] = {};

  for (int k0 = 0; k0 < K; k0 += 32) {
    // stage A: 64 rows x 32 k (bf16), one 16B load per thread
    {
      int row = t >> 2;
      int kc = (t & 3) * 8;
      bf16x8 va = *(const bf16x8*)&A[(size_t)(m0 + row) * K + k0 + kc];
      *(bf16x8*)&As[row][kc] = va;
    }
    // stage B transposed: 32 k-rows x 64 n (f32 -> bf16)
    {
      int krow = t >> 3;
      int nc = (t & 7) * 8;
      const float* src = &B[(size_t)(k0 + krow) * N + n0 + nc];
#pragma unroll
      for (int i = 0; i < 8; ++i) {
        int n = n0 + nc + i;
        float vv = (n < N) ? src[i] : 0.f;
        Bs[nc + i][krow] = (bf16_t)vv;
      }
    }
    __syncthreads();
#pragma unroll
    for (int i = 0; i < 2; ++i) {
      bf16x8 a = *(const bf16x8*)&As[wr + i * 16 + r16][h * 8];
#pragma unroll
      for (int j = 0; j < 2; ++j) {
        bf16x8 b = *(const bf16x8*)&Bs[wc + j * 16 + r16][h * 8];
        acc[i][j] = __builtin_amdgcn_mfma_f32_16x16x32_bf16(a, b, acc[i][j], 0, 0, 0);
      }
    }
    __syncthreads();
  }

#pragma unroll
  for (int i = 0; i < 2; ++i)
#pragma unroll
    for (int j = 0; j < 2; ++j)
#pragma unroll
      for (int r = 0; r < 4; ++r) {
        int row = m0 + wr + i * 16 + h * 4 + r;
        int col = n0 + wc + j * 16 + r16;
        if (col < N) {
          float vv = acc[i][j][r];
          size_t idx = (size_t)row * N + col;
          if (OUTMODE == 0) Cf[idx] = vv;
          else if (OUTMODE == 1) Cb[idx] = (bf16_t)vv;
          else Cf[idx] += vv;
        }
      }
}

// ---------------- RoPE (f32 q,k -> bf16 q,k) ----------------
__global__ __launch_bounds__(256) void k_rope(const float* __restrict__ qf,
                                              const float* __restrict__ kf,
                                              bf16_t* __restrict__ qb,
                                              bf16_t* __restrict__ kb) {
  int id = blockIdx.x * 256 + threadIdx.x;   // SEQ*NH*32 total
  int i = id & 31;
  int head = (id >> 5) & 15;
  int s = id >> 9;
  float ang = (float)s * powf(10000.f, -(float)i * (1.f / 32.f));
  float sn, cs;
  sincosf(ang, &sn, &cs);
  size_t base = (size_t)s * DIM + head * HD + i;
  float q0 = qf[base], q1 = qf[base + 32];
  qb[base]      = (bf16_t)(q0 * cs - q1 * sn);
  qb[base + 32] = (bf16_t)(q1 * cs + q0 * sn);
  float k0 = kf[base], k1 = kf[base + 32];
  kb[base]      = (bf16_t)(k0 * cs - k1 * sn);
  kb[base + 32] = (bf16_t)(k1 * cs + k0 * sn);
}

// ---------------- flash attention, 1 wave per (16-row q-tile, head) ----------------
__global__ __launch_bounds__(64) void k_attn(const bf16_t* __restrict__ qb,
                                             const bf16_t* __restrict__ kb,
                                             const bf16_t* __restrict__ vb,
                                             bf16_t* __restrict__ ao) {
  __shared__ bf16_t Pl[16][40];
  __shared__ bf16_t Vt[64][40];   // Vt[dh_col][k_row] for current 32-chunk
  const int qt = blockIdx.x;
  const int head = blockIdx.y;
  const int l = threadIdx.x;
  const int h = l >> 4;
  const int r16 = l & 15;
  const int q0 = qt * 16;
  const size_t hoff = (size_t)head * HD;

  bf16x8 aq[2];
#pragma unroll
  for (int c = 0; c < 2; ++c)
    aq[c] = *(const bf16x8*)&qb[(size_t)(q0 + r16) * DIM + hoff + c * 32 + h * 8];

  f32x4 o[4] = {};
  float mrow[4], lrow[4];
#pragma unroll
  for (int r = 0; r < 4; ++r) { mrow[r] = -1e30f; lrow[r] = 0.f; }

  const int kmax = q0 + 15;
  for (int k0 = 0; k0 <= kmax; k0 += 32) {
    // scores: 2 col-tiles of 16
    f32x4 sc[2];
#pragma unroll
    for (int tc = 0; tc < 2; ++tc) {
      f32x4 z = {};
      bf16x8 b0 = *(const bf16x8*)&kb[(size_t)(k0 + tc * 16 + r16) * DIM + hoff + 0 + h * 8];
      bf16x8 b1 = *(const bf16x8*)&kb[(size_t)(k0 + tc * 16 + r16) * DIM + hoff + 32 + h * 8];
      z = __builtin_amdgcn_mfma_f32_16x16x32_bf16(aq[0], b0, z, 0, 0, 0);
      z = __builtin_amdgcn_mfma_f32_16x16x32_bf16(aq[1], b1, z, 0, 0, 0);
      sc[tc] = z;
    }
    // stage V chunk transposed: Vt[col][k]
#pragma unroll
    for (int i = 0; i < 4; ++i) {
      int krow = l & 31;
      int seg = (l >> 5) * 32 + i * 8;
      bf16x8 vv = *(const bf16x8*)&vb[(size_t)(k0 + krow) * DIM + hoff + seg];
#pragma unroll
      for (int j = 0; j < 8; ++j) Vt[seg + j][krow] = vv[j];
    }
    // mask + online softmax
#pragma unroll
    for (int tc = 0; tc < 2; ++tc)
#pragma unroll
      for (int r = 0; r < 4; ++r) {
        int row = q0 + h * 4 + r;
        int col = k0 + tc * 16 + r16;
        float v = sc[tc][r] * 0.125f;
        if (col > row) v = -1e30f;
        sc[tc][r] = v;
      }
#pragma unroll
    for (int r = 0; r < 4; ++r) {
      float mx = fmaxf(sc[0][r], sc[1][r]);
#pragma unroll
      for (int d = 1; d < 16; d <<= 1) mx = fmaxf(mx, __shfl_xor(mx, d));
      float mnew = fmaxf(mrow[r], mx);
      float alpha = expf(mrow[r] - mnew);
      float p0 = expf(sc[0][r] - mnew);
      float p1 = expf(sc[1][r] - mnew);
      float ssum = p0 + p1;
#pragma unroll
      for (int d = 1; d < 16; d <<= 1) ssum += __shfl_xor(ssum, d);
      lrow[r] = lrow[r] * alpha + ssum;
      mrow[r] = mnew;
#pragma unroll
      for (int ct = 0; ct < 4; ++ct) o[ct][r] *= alpha;
      Pl[h * 4 + r][r16]      = (bf16_t)p0;
      Pl[h * 4 + r][16 + r16] = (bf16_t)p1;
    }
    __syncthreads();
    // PV
    bf16x8 pa = *(const bf16x8*)&Pl[r16][h * 8];
#pragma unroll
    for (int ct = 0; ct < 4; ++ct) {
      bf16x8 bv = *(const bf16x8*)&Vt[ct * 16 + r16][h * 8];
      o[ct] = __builtin_amdgcn_mfma_f32_16x16x32_bf16(pa, bv, o[ct], 0, 0, 0);
    }
    __syncthreads();
  }
#pragma unroll
  for (int ct = 0; ct < 4; ++ct)
#pragma unroll
    for (int r = 0; r < 4; ++r) {
      int row = q0 + h * 4 + r;
      float vv = o[ct][r] / lrow[r];
      ao[(size_t)row * DIM + hoff + ct * 16 + r16] = (bf16_t)vv;
    }
}

// ---------------- silu(g1) * g3 -> bf16 ----------------
__global__ __launch_bounds__(256) void k_gate(const float* __restrict__ g1,
                                              const float* __restrict__ g3,
                                              bf16_t* __restrict__ out, int n) {
  int i = blockIdx.x * 256 + threadIdx.x;
  if (i < n) {
    float a = g1[i];
    float sv = a / (1.f + expf(-a));
    out[i] = (bf16_t)(sv * g3[i]);
  }
}

extern "C" void kernel_launch(void* const* d_in, const int* in_sizes, int n_in,
                              void* d_out, int out_size, void* d_ws, size_t ws_size,
                              hipStream_t stream) {
  const int*   ids  = (const int*)d_in[0];
  const float* temb = (const float*)d_in[1];
  const float* Wq   = (const float*)d_in[2];
  const float* Wk   = (const float*)d_in[3];
  const float* Wv   = (const float*)d_in[4];
  const float* Wo   = (const float*)d_in[5];
  const float* ln1s = (const float*)d_in[6];
  const float* ln1b = (const float*)d_in[7];
  const float* ln2s = (const float*)d_in[8];
  const float* ln2b = (const float*)d_in[9];
  const float* w1   = (const float*)d_in[10];
  const float* w2   = (const float*)d_in[11];
  const float* w3   = (const float*)d_in[12];
  const float* lnfs = (const float*)d_in[13];
  const float* lnfb = (const float*)d_in[14];
  const float* lmh  = (const float*)d_in[15];
  float* out = (float*)d_out;

  char* p = (char*)d_ws;
  auto alloc = [&](size_t bytes) { void* r = (void*)p; p += (bytes + 255) & ~(size_t)255; return r; };
  float*  x     = (float*)alloc((size_t)SEQ * DIM * 4);
  bf16_t* hb    = (bf16_t*)alloc((size_t)SEQ * DIM * 2);
  float*  qf    = (float*)alloc((size_t)SEQ * DIM * 4);
  float*  kf    = (float*)alloc((size_t)SEQ * DIM * 4);
  bf16_t* qb2   = (bf16_t*)alloc((size_t)SEQ * DIM * 2);
  bf16_t* kb2   = (bf16_t*)alloc((size_t)SEQ * DIM * 2);
  bf16_t* vb2   = (bf16_t*)alloc((size_t)SEQ * DIM * 2);
  bf16_t* aob   = (bf16_t*)alloc((size_t)SEQ * DIM * 2);
  float*  g1    = (float*)alloc((size_t)SEQ * FF * 4);
  float*  g3    = (float*)alloc((size_t)SEQ * FF * 4);
  bf16_t* gateb = (bf16_t*)alloc((size_t)SEQ * FF * 2);

  k_embed<<<SEQ, 256, 0, stream>>>(ids, temb, x);

  dim3 gDD(DIM / 64, SEQ / 64);
  dim3 gDF(FF / 64, SEQ / 64);
  dim3 gAt(SEQ / 16, NH);
  for (int l = 0; l < NL; ++l) {
    k_ln<<<SEQ, 64, 0, stream>>>(x, ln1s + (size_t)l * DIM, ln1b + (size_t)l * DIM, hb);
    k_gemm<0><<<gDD, 256, 0, stream>>>(hb, Wq + (size_t)l * DIM * DIM, qf, nullptr, SEQ, DIM, DIM);
    k_gemm<0><<<gDD, 256, 0, stream>>>(hb, Wk + (size_t)l * DIM * DIM, kf, nullptr, SEQ, DIM, DIM);
    k_gemm<1><<<gDD, 256, 0, stream>>>(hb, Wv + (size_t)l * DIM * DIM, nullptr, vb2, SEQ, DIM, DIM);
    k_rope<<<(SEQ * NH * 32) / 256, 256, 0, stream>>>(qf, kf, qb2, kb2);
    k_attn<<<gAt, 64, 0, stream>>>(qb2, kb2, vb2, aob);
    k_gemm<2><<<gDD, 256, 0, stream>>>(aob, Wo + (size_t)l * DIM * DIM, x, nullptr, SEQ, DIM, DIM);
    k_ln<<<SEQ, 64, 0, stream>>>(x, ln2s + (size_t)l * DIM, ln2b + (size_t)l * DIM, hb);
    k_gemm<0><<<gDF, 256, 0, stream>>>(hb, w1 + (size_t)l * DIM * FF, g1, nullptr, SEQ, FF, DIM);
    k_gemm<0><<<gDF, 256, 0, stream>>>(hb, w3 + (size_t)l * DIM * FF, g3, nullptr, SEQ, FF, DIM);
    k_gate<<<(SEQ * FF) / 256, 256, 0, stream>>>(g1, g3, gateb, SEQ * FF);
    k_gemm<2><<<gDD, 256, 0, stream>>>(gateb, w2 + (size_t)l * FF * DIM, x, nullptr, SEQ, DIM, FF);
  }
  k_ln<<<SEQ, 64, 0, stream>>>(x, lnfs, lnfb, hb);
  dim3 gV((VOC + 63) / 64, SEQ / 64);
  k_gemm<0><<<gV, 256, 0, stream>>>(hb, lmh, out, nullptr, SEQ, VOC, DIM);
}

// Round 2
// 5380.008 us; speedup vs baseline: 2.8190x; 2.8190x over previous
//
#include <hip/hip_runtime.h>
#include <math.h>

// ---- problem constants ----
constexpr int SEQ = 2048;
constexpr int DIM = 1024;
constexpr int NH  = 16;
constexpr int HD  = 64;
constexpr int FF  = 4096;
constexpr int NL  = 12;
constexpr int VOC = 1400;
constexpr int VOCP = 1408;   // padded to 64

typedef __bf16 bf16_t;
typedef __bf16 bf16x8 __attribute__((ext_vector_type(8)));
typedef float  f32x4  __attribute__((ext_vector_type(4)));

typedef __attribute__((address_space(1))) const void GV;
typedef __attribute__((address_space(3))) void LV;

__device__ __forceinline__ void gll16(const bf16_t* g, bf16_t* l) {
  __builtin_amdgcn_global_load_lds((GV*)g, (LV*)l, 16, 0, 0);
}

// ---------------- embedding gather ----------------
__global__ __launch_bounds__(256) void k_embed(const int* __restrict__ ids,
                                               const float* __restrict__ emb,
                                               float* __restrict__ x) {
  int s = blockIdx.x;
  int d = threadIdx.x * 4;
  const float4 v = *(const float4*)&emb[(size_t)ids[s] * DIM + d];
  *(float4*)&x[(size_t)s * DIM + d] = v;
}

// ---------------- layernorm (f32 in -> bf16 out), 1 wave per row ----------------
__global__ __launch_bounds__(64) void k_ln(const float* __restrict__ x,
                                           const float* __restrict__ sc,
                                           const float* __restrict__ bi,
                                           bf16_t* __restrict__ out) {
  int s = blockIdx.x;
  int l = threadIdx.x;
  const float* xr = x + (size_t)s * DIM;
  float4 v[4];
  float sum = 0.f, sq = 0.f;
#pragma unroll
  for (int i = 0; i < 4; ++i) {
    v[i] = *(const float4*)&xr[i * 256 + l * 4];
#pragma unroll
    for (int j = 0; j < 4; ++j) { sum += v[i][j]; sq += v[i][j] * v[i][j]; }
  }
#pragma unroll
  for (int d = 1; d < 64; d <<= 1) {
    sum += __shfl_xor(sum, d);
    sq  += __shfl_xor(sq, d);
  }
  float mean = sum * (1.f / DIM);
  float var  = sq * (1.f / DIM) - mean * mean;
  float inv  = rsqrtf(var + 1e-5f);
#pragma unroll
  for (int i = 0; i < 4; ++i) {
    int off = i * 256 + l * 4;
    float4 scv = *(const float4*)&sc[off];
    float4 biv = *(const float4*)&bi[off];
#pragma unroll
    for (int j = 0; j < 4; ++j) {
      float o = (v[i][j] - mean) * inv * scv[j] + biv[j];
      out[(size_t)s * DIM + off + j] = (bf16_t)o;
    }
  }
}

// ---------------- weight convert + transpose: src[K][N] f32 -> dst[Npad][K] bf16 ----
// blockIdx.z = matrix index (layer). Zero-fills rows n >= N.
__global__ __launch_bounds__(256) void k_cvt_t(const float* __restrict__ src,
                                               bf16_t* __restrict__ dst,
                                               int K_, int N_, int Npad_) {
  __shared__ bf16_t T[64][66];   // T[n][k], +2 pad: 2-way max on column writes
  const int k0 = blockIdx.y * 64;
  const int n0 = blockIdx.x * 64;
  const size_t so = (size_t)blockIdx.z * K_ * N_;
  const size_t dо = (size_t)blockIdx.z * Npad_ * K_;
  const int t = threadIdx.x;
  const int kk = t >> 4;
  const int nn = (t & 15) * 4;
#pragma unroll
  for (int it = 0; it < 4; ++it) {
    int krow = kk + it * 16;
    float4 v = {0.f, 0.f, 0.f, 0.f};
    if (n0 + nn < N_) v = *(const float4*)&src[so + (size_t)(k0 + krow) * N_ + n0 + nn];
#pragma unroll
    for (int q = 0; q < 4; ++q) T[nn + q][krow] = (bf16_t)v[q];
  }
  __syncthreads();
#pragma unroll
  for (int it = 0; it < 4; ++it) {
    int c = it * 256 + t;
    int nr = c >> 4;
    int kc = (c & 15) * 4;
    ushort4 o = *(const ushort4*)&T[nr][kc];
    *(ushort4*)&dst[dо + (size_t)(n0 + nr) * K_ + k0 + kc] = o;
  }
}

// ---------------- GEMM (m97 structure): C[M,N] = A[M,K] * Bt[N][K], bf16 MFMA ----
// tile 128 x TN, BK=32, 4 waves (2x2). OUTMODE 0: f32 store, 1: bf16 store, 2: f32 +=
template <int TN, int OUTMODE>
__global__ __launch_bounds__(256) void k_gemm2(const bf16_t* __restrict__ A,
                                               const bf16_t* __restrict__ Bt,
                                               float* __restrict__ Cf,
                                               bf16_t* __restrict__ Cb,
                                               int M, int N, int K) {
  constexpr int JN = TN / 32;            // B frags per wave
  __shared__ bf16_t As[128 * 32];
  __shared__ bf16_t Bs[TN * 32];
  const int t = threadIdx.x;
  const int w = t >> 6, l = t & 63;
  const int h = l >> 4, r16 = l & 15;
  const int m0 = blockIdx.y * 128, n0 = blockIdx.x * TN;
  const int wr = (w >> 1) * 64;
  const int wc = (w & 1) * (TN / 2);
  const int srow = l >> 2;               // 0..15
  const int skc  = (l & 3) * 8;          // 0,8,16,24

  f32x4 acc[4][JN] = {};

  const bf16_t* pa = &A[(size_t)(m0 + w * 16 + srow) * K + skc];
  const bf16_t* pb = &Bt[(size_t)(n0 + w * 16 + srow) * K + skc];

  for (int k0 = 0; k0 < K; k0 += 32) {
    gll16(pa + k0, &As[(w * 16) * 32]);
    gll16(pa + (size_t)64 * K + k0, &As[(64 + w * 16) * 32]);
    gll16(pb + k0, &Bs[(w * 16) * 32]);
    if constexpr (TN == 128) {
      gll16(pb + (size_t)64 * K + k0, &Bs[(64 + w * 16) * 32]);
    }
    __syncthreads();
    bf16x8 af[4], bfr[JN];
#pragma unroll
    for (int i = 0; i < 4; ++i)
      af[i] = *(const bf16x8*)&As[(wr + i * 16 + r16) * 32 + h * 8];
#pragma unroll
    for (int j = 0; j < JN; ++j)
      bfr[j] = *(const bf16x8*)&Bs[(wc + j * 16 + r16) * 32 + h * 8];
#pragma unroll
    for (int i = 0; i < 4; ++i)
#pragma unroll
      for (int j = 0; j < JN; ++j)
        acc[i][j] = __builtin_amdgcn_mfma_f32_16x16x32_bf16(af[i], bfr[j], acc[i][j], 0, 0, 0);
    __syncthreads();
  }

#pragma unroll
  for (int i = 0; i < 4; ++i)
#pragma unroll
    for (int j = 0; j < JN; ++j)
#pragma unroll
      for (int r = 0; r < 4; ++r) {
        int row = m0 + wr + i * 16 + h * 4 + r;
        int col = n0 + wc + j * 16 + r16;
        if (col < N) {
          float vv = acc[i][j][r];
          size_t idx = (size_t)row * N + col;
          if (OUTMODE == 0) Cf[idx] = vv;
          else if (OUTMODE == 1) Cb[idx] = (bf16_t)vv;
          else Cf[idx] += vv;
        }
      }
}

// ---------------- RoPE (f32 q,k -> bf16 q,k) ----------------
__global__ __launch_bounds__(256) void k_rope(const float* __restrict__ qf,
                                              const float* __restrict__ kf,
                                              bf16_t* __restrict__ qb,
                                              bf16_t* __restrict__ kb) {
  int id = blockIdx.x * 256 + threadIdx.x;   // SEQ*NH*32 total
  int i = id & 31;
  int head = (id >> 5) & 15;
  int s = id >> 9;
  float ang = (float)s * powf(10000.f, -(float)i * (1.f / 32.f));
  float sn, cs;
  sincosf(ang, &sn, &cs);
  size_t base = (size_t)s * DIM + head * HD + i;
  float q0 = qf[base], q1 = qf[base + 32];
  qb[base]      = (bf16_t)(q0 * cs - q1 * sn);
  qb[base + 32] = (bf16_t)(q1 * cs + q0 * sn);
  float k0 = kf[base], k1 = kf[base + 32];
  kb[base]      = (bf16_t)(k0 * cs - k1 * sn);
  kb[base + 32] = (bf16_t)(k1 * cs + k0 * sn);
}

// ---------------- flash attention, 1 wave per (16-row q-tile, head) ----------------
__global__ __launch_bounds__(64) void k_attn(const bf16_t* __restrict__ qb,
                                             const bf16_t* __restrict__ kb,
                                             const bf16_t* __restrict__ vb,
                                             bf16_t* __restrict__ ao) {
  __shared__ bf16_t Pl[16][40];
  __shared__ bf16_t Vt[64][40];   // Vt[dh_col][k_row] for current 32-chunk
  const int qt = blockIdx.x;
  const int head = blockIdx.y;
  const int l = threadIdx.x;
  const int h = l >> 4;
  const int r16 = l & 15;
  const int q0 = qt * 16;
  const size_t hoff = (size_t)head * HD;

  bf16x8 aq[2];
#pragma unroll
  for (int c = 0; c < 2; ++c)
    aq[c] = *(const bf16x8*)&qb[(size_t)(q0 + r16) * DIM + hoff + c * 32 + h * 8];

  f32x4 o[4] = {};
  float mrow[4], lrow[4];
#pragma unroll
  for (int r = 0; r < 4; ++r) { mrow[r] = -1e30f; lrow[r] = 0.f; }

  const int kmax = q0 + 15;
  for (int k0 = 0; k0 <= kmax; k0 += 32) {
    f32x4 sc[2];
#pragma unroll
    for (int tc = 0; tc < 2; ++tc) {
      f32x4 z = {};
      bf16x8 b0 = *(const bf16x8*)&kb[(size_t)(k0 + tc * 16 + r16) * DIM + hoff + 0 + h * 8];
      bf16x8 b1 = *(const bf16x8*)&kb[(size_t)(k0 + tc * 16 + r16) * DIM + hoff + 32 + h * 8];
      z = __builtin_amdgcn_mfma_f32_16x16x32_bf16(aq[0], b0, z, 0, 0, 0);
      z = __builtin_amdgcn_mfma_f32_16x16x32_bf16(aq[1], b1, z, 0, 0, 0);
      sc[tc] = z;
    }
#pragma unroll
    for (int i = 0; i < 4; ++i) {
      int krow = l & 31;
      int seg = (l >> 5) * 32 + i * 8;
      bf16x8 vv = *(const bf16x8*)&vb[(size_t)(k0 + krow) * DIM + hoff + seg];
#pragma unroll
      for (int j = 0; j < 8; ++j) Vt[seg + j][krow] = vv[j];
    }
#pragma unroll
    for (int tc = 0; tc < 2; ++tc)
#pragma unroll
      for (int r = 0; r < 4; ++r) {
        int row = q0 + h * 4 + r;
        int col = k0 + tc * 16 + r16;
        float v = sc[tc][r] * 0.125f;
        if (col > row) v = -1e30f;
        sc[tc][r] = v;
      }
#pragma unroll
    for (int r = 0; r < 4; ++r) {
      float mx = fmaxf(sc[0][r], sc[1][r]);
#pragma unroll
      for (int d = 1; d < 16; d <<= 1) mx = fmaxf(mx, __shfl_xor(mx, d));
      float mnew = fmaxf(mrow[r], mx);
      float alpha = expf(mrow[r] - mnew);
      float p0 = expf(sc[0][r] - mnew);
      float p1 = expf(sc[1][r] - mnew);
      float ssum = p0 + p1;
#pragma unroll
      for (int d = 1; d < 16; d <<= 1) ssum += __shfl_xor(ssum, d);
      lrow[r] = lrow[r] * alpha + ssum;
      mrow[r] = mnew;
#pragma unroll
      for (int ct = 0; ct < 4; ++ct) o[ct][r] *= alpha;
      Pl[h * 4 + r][r16]      = (bf16_t)p0;
      Pl[h * 4 + r][16 + r16] = (bf16_t)p1;
    }
    __syncthreads();
    bf16x8 pa = *(const bf16x8*)&Pl[r16][h * 8];
#pragma unroll
    for (int ct = 0; ct < 4; ++ct) {
      bf16x8 bv = *(const bf16x8*)&Vt[ct * 16 + r16][h * 8];
      o[ct] = __builtin_amdgcn_mfma_f32_16x16x32_bf16(pa, bv, o[ct], 0, 0, 0);
    }
    __syncthreads();
  }
#pragma unroll
  for (int ct = 0; ct < 4; ++ct)
#pragma unroll
    for (int r = 0; r < 4; ++r) {
      int row = q0 + h * 4 + r;
      float vv = o[ct][r] / lrow[r];
      ao[(size_t)row * DIM + hoff + ct * 16 + r16] = (bf16_t)vv;
    }
}

// ---------------- silu(g1) * g3 -> bf16 ----------------
__global__ __launch_bounds__(256) void k_gate(const float* __restrict__ g1,
                                              const float* __restrict__ g3,
                                              bf16_t* __restrict__ out, int n) {
  int i = blockIdx.x * 256 + threadIdx.x;
  if (i < n) {
    float a = g1[i];
    float sv = a / (1.f + expf(-a));
    out[i] = (bf16_t)(sv * g3[i]);
  }
}

extern "C" void kernel_launch(void* const* d_in, const int* in_sizes, int n_in,
                              void* d_out, int out_size, void* d_ws, size_t ws_size,
                              hipStream_t stream) {
  const int*   ids  = (const int*)d_in[0];
  const float* temb = (const float*)d_in[1];
  const float* Wq   = (const float*)d_in[2];
  const float* Wk   = (const float*)d_in[3];
  const float* Wv   = (const float*)d_in[4];
  const float* Wo   = (const float*)d_in[5];
  const float* ln1s = (const float*)d_in[6];
  const float* ln1b = (const float*)d_in[7];
  const float* ln2s = (const float*)d_in[8];
  const float* ln2b = (const float*)d_in[9];
  const float* w1   = (const float*)d_in[10];
  const float* w2   = (const float*)d_in[11];
  const float* w3   = (const float*)d_in[12];
  const float* lnfs = (const float*)d_in[13];
  const float* lnfb = (const float*)d_in[14];
  const float* lmh  = (const float*)d_in[15];
  float* out = (float*)d_out;

  char* p = (char*)d_ws;
  size_t used = 0;
  auto alloc = [&](size_t bytes) {
    void* r = (void*)p;
    size_t a = (bytes + 255) & ~(size_t)255;
    p += a; used += a;
    return r;
  };
  // activations
  float*  x     = (float*)alloc((size_t)SEQ * DIM * 4);
  bf16_t* hb    = (bf16_t*)alloc((size_t)SEQ * DIM * 2);
  float*  qf    = (float*)alloc((size_t)SEQ * DIM * 4);
  float*  kf    = (float*)alloc((size_t)SEQ * DIM * 4);
  bf16_t* qb2   = (bf16_t*)alloc((size_t)SEQ * DIM * 2);
  bf16_t* kb2   = (bf16_t*)alloc((size_t)SEQ * DIM * 2);
  bf16_t* vb2   = (bf16_t*)alloc((size_t)SEQ * DIM * 2);
  bf16_t* aob   = (bf16_t*)alloc((size_t)SEQ * DIM * 2);
  float*  g1    = (float*)alloc((size_t)SEQ * FF * 4);
  float*  g3    = (float*)alloc((size_t)SEQ * FF * 4);
  bf16_t* gateb = (bf16_t*)alloc((size_t)SEQ * FF * 2);

  const size_t szDD = (size_t)DIM * DIM;           // 1M elems
  const size_t szDF = (size_t)DIM * FF;            // 4M elems
  const size_t wt_bytes = (4 * (size_t)NL * szDD + 3 * (size_t)NL * szDF + (size_t)VOCP * DIM) * 2;
  const bool bigws = (ws_size >= used + wt_bytes + (1u << 20));

  bf16_t *bWq, *bWk, *bWv, *bWo, *bw1, *bw2, *bw3, *blm, *wscratch = nullptr;
  if (bigws) {
    bWq = (bf16_t*)alloc(NL * szDD * 2);
    bWk = (bf16_t*)alloc(NL * szDD * 2);
    bWv = (bf16_t*)alloc(NL * szDD * 2);
    bWo = (bf16_t*)alloc(NL * szDD * 2);
    bw1 = (bf16_t*)alloc(NL * szDF * 2);
    bw2 = (bf16_t*)alloc(NL * szDF * 2);
    bw3 = (bf16_t*)alloc(NL * szDF * 2);
    blm = (bf16_t*)alloc((size_t)VOCP * DIM * 2);
  } else {
    wscratch = (bf16_t*)alloc(szDF * 2);   // one weight at a time
    bWq = bWk = bWv = bWo = bw1 = bw2 = bw3 = blm = wscratch;
  }

  auto cvt = [&](const float* src, bf16_t* dst, int K_, int N_, int Npad_, int nz) {
    dim3 g(Npad_ / 64, K_ / 64, nz);
    k_cvt_t<<<g, 256, 0, stream>>>(src, dst, K_, N_, Npad_);
  };

  if (bigws) {
    cvt(Wq, bWq, DIM, DIM, DIM, NL);
    cvt(Wk, bWk, DIM, DIM, DIM, NL);
    cvt(Wv, bWv, DIM, DIM, DIM, NL);
    cvt(Wo, bWo, DIM, DIM, DIM, NL);
    cvt(w1, bw1, DIM, FF, FF, NL);
    cvt(w3, bw3, DIM, FF, FF, NL);
    cvt(w2, bw2, FF, DIM, DIM, NL);
    cvt(lmh, blm, DIM, VOC, VOCP, 1);
  }
  // weight pointer for (big buf, f32 src, layer, dims); converts JIT if small ws
  auto wp = [&](bf16_t* big, const float* src, int lyr, int K_, int N_, int Npad_) -> bf16_t* {
    if (bigws) return big + (size_t)lyr * Npad_ * K_;
    cvt(src + (size_t)lyr * K_ * N_, wscratch, K_, N_, Npad_, 1);
    return wscratch;
  };

  k_embed<<<SEQ, 256, 0, stream>>>(ids, temb, x);

  dim3 gDD(DIM / 64, SEQ / 128);     // TN=64 tiles: 16x16 = 256 blocks
  dim3 gDF(FF / 128, SEQ / 128);     // TN=128 tiles: 32x16 = 512 blocks
  dim3 gLM(VOCP / 64, SEQ / 128);    // 22x16 = 352 blocks
  dim3 gAt(SEQ / 16, NH);

  for (int l = 0; l < NL; ++l) {
    k_ln<<<SEQ, 64, 0, stream>>>(x, ln1s + (size_t)l * DIM, ln1b + (size_t)l * DIM, hb);
    k_gemm2<64, 0><<<gDD, 256, 0, stream>>>(hb, wp(bWq, Wq, l, DIM, DIM, DIM), qf, nullptr, SEQ, DIM, DIM);
    k_gemm2<64, 0><<<gDD, 256, 0, stream>>>(hb, wp(bWk, Wk, l, DIM, DIM, DIM), kf, nullptr, SEQ, DIM, DIM);
    k_gemm2<64, 1><<<gDD, 256, 0, stream>>>(hb, wp(bWv, Wv, l, DIM, DIM, DIM), nullptr, vb2, SEQ, DIM, DIM);
    k_rope<<<(SEQ * NH * 32) / 256, 256, 0, stream>>>(qf, kf, qb2, kb2);
    k_attn<<<gAt, 64, 0, stream>>>(qb2, kb2, vb2, aob);
    k_gemm2<64, 2><<<gDD, 256, 0, stream>>>(aob, wp(bWo, Wo, l, DIM, DIM, DIM), x, nullptr, SEQ, DIM, DIM);
    k_ln<<<SEQ, 64, 0, stream>>>(x, ln2s + (size_t)l * DIM, ln2b + (size_t)l * DIM, hb);
    k_gemm2<128, 0><<<gDF, 256, 0, stream>>>(hb, wp(bw1, w1, l, DIM, FF, FF), g1, nullptr, SEQ, FF, DIM);
    k_gemm2<128, 0><<<gDF, 256, 0, stream>>>(hb, wp(bw3, w3, l, DIM, FF, FF), g3, nullptr, SEQ, FF, DIM);
    k_gate<<<(SEQ * FF) / 256, 256, 0, stream>>>(g1, g3, gateb, SEQ * FF);
    k_gemm2<64, 2><<<gDD, 256, 0, stream>>>(gateb, wp(bw2, w2, l, FF, DIM, DIM), x, nullptr, SEQ, DIM, FF);
  }
  k_ln<<<SEQ, 64, 0, stream>>>(x, lnfs, lnfb, hb);
  k_gemm2<64, 0><<<gLM, 256, 0, stream>>>(hb, bigws ? blm : wp(blm, lmh, 0, DIM, VOC, VOCP), out, nullptr, SEQ, VOC, DIM);
}

// Round 3
// 4742.922 us; speedup vs baseline: 3.1976x; 1.1343x over previous
//
#include <hip/hip_runtime.h>
#include <math.h>

// ---- problem constants ----
constexpr int SEQ = 2048;
constexpr int DIM = 1024;
constexpr int NH  = 16;
constexpr int HD  = 64;
constexpr int FF  = 4096;
constexpr int NL  = 12;
constexpr int VOC = 1400;
constexpr int VOCP = 1408;   // padded to 64

typedef __bf16 bf16_t;
typedef __bf16 bf16x8 __attribute__((ext_vector_type(8)));
typedef float  f32x4  __attribute__((ext_vector_type(4)));

typedef __attribute__((address_space(1))) const void GV;
typedef __attribute__((address_space(3))) void LV;

__device__ __forceinline__ void gll16(const bf16_t* g, bf16_t* l) {
  __builtin_amdgcn_global_load_lds((GV*)g, (LV*)l, 16, 0, 0);
}

// ---------------- embedding gather ----------------
__global__ __launch_bounds__(256) void k_embed(const int* __restrict__ ids,
                                               const float* __restrict__ emb,
                                               float* __restrict__ x) {
  int s = blockIdx.x;
  int d = threadIdx.x * 4;
  const float4 v = *(const float4*)&emb[(size_t)ids[s] * DIM + d];
  *(float4*)&x[(size_t)s * DIM + d] = v;
}

// ---------------- layernorm (f32 in -> bf16 out), 1 wave per row ----------------
__global__ __launch_bounds__(64) void k_ln(const float* __restrict__ x,
                                           const float* __restrict__ sc,
                                           const float* __restrict__ bi,
                                           bf16_t* __restrict__ out) {
  int s = blockIdx.x;
  int l = threadIdx.x;
  const float* xr = x + (size_t)s * DIM;
  float4 v[4];
  float sum = 0.f, sq = 0.f;
#pragma unroll
  for (int i = 0; i < 4; ++i) {
    v[i] = *(const float4*)&xr[i * 256 + l * 4];
#pragma unroll
    for (int j = 0; j < 4; ++j) { sum += v[i][j]; sq += v[i][j] * v[i][j]; }
  }
#pragma unroll
  for (int d = 1; d < 64; d <<= 1) {
    sum += __shfl_xor(sum, d);
    sq  += __shfl_xor(sq, d);
  }
  float mean = sum * (1.f / DIM);
  float var  = sq * (1.f / DIM) - mean * mean;
  float inv  = rsqrtf(var + 1e-5f);
#pragma unroll
  for (int i = 0; i < 4; ++i) {
    int off = i * 256 + l * 4;
    float4 scv = *(const float4*)&sc[off];
    float4 biv = *(const float4*)&bi[off];
#pragma unroll
    for (int j = 0; j < 4; ++j) {
      float o = (v[i][j] - mean) * inv * scv[j] + biv[j];
      out[(size_t)s * DIM + off + j] = (bf16_t)o;
    }
  }
}

// ---------------- weight convert + transpose: src[K][N] f32 -> dst[Npad][K] bf16 ----
__global__ __launch_bounds__(256) void k_cvt_t(const float* __restrict__ src,
                                               bf16_t* __restrict__ dst,
                                               int K_, int N_, int Npad_) {
  __shared__ bf16_t T[64][66];
  const int k0 = blockIdx.y * 64;
  const int n0 = blockIdx.x * 64;
  const size_t so = (size_t)blockIdx.z * K_ * N_;
  const size_t dof = (size_t)blockIdx.z * Npad_ * K_;
  const int t = threadIdx.x;
  const int kk = t >> 4;
  const int nn = (t & 15) * 4;
#pragma unroll
  for (int it = 0; it < 4; ++it) {
    int krow = kk + it * 16;
    float4 v = {0.f, 0.f, 0.f, 0.f};
    if (n0 + nn < N_) v = *(const float4*)&src[so + (size_t)(k0 + krow) * N_ + n0 + nn];
#pragma unroll
    for (int q = 0; q < 4; ++q) T[nn + q][krow] = (bf16_t)v[q];
  }
  __syncthreads();
#pragma unroll
  for (int it = 0; it < 4; ++it) {
    int c = it * 256 + t;
    int nr = c >> 4;
    int kc = (c & 15) * 4;
    ushort4 o = *(const ushort4*)&T[nr][kc];
    *(ushort4*)&dst[dof + (size_t)(n0 + nr) * K_ + k0 + kc] = o;
  }
}

// ---------------- GEMM (m97 structure): C[M,N] = A[M,K] * Bt[N][K], bf16 MFMA ----
// tile 128 x TN, BK=32, 4 waves (2x2).
// OUTMODE 0: f32 store, 1: bf16 store, 2: f32 +=, 3: bf16 silu(Cf[idx])*acc store
template <int TN, int OUTMODE>
__global__ __launch_bounds__(256) void k_gemm2(const bf16_t* __restrict__ A,
                                               const bf16_t* __restrict__ Bt,
                                               float* __restrict__ Cf,
                                               bf16_t* __restrict__ Cb,
                                               int M, int N, int K) {
  constexpr int JN = TN / 32;            // B frags per wave
  __shared__ bf16_t As[128 * 32];
  __shared__ bf16_t Bs[TN * 32];
  const int t = threadIdx.x;
  const int w = t >> 6, l = t & 63;
  const int h = l >> 4, r16 = l & 15;
  const int m0 = blockIdx.y * 128, n0 = blockIdx.x * TN;
  const int wr = (w >> 1) * 64;
  const int wc = (w & 1) * (TN / 2);
  const int srow = l >> 2;               // 0..15
  const int skc  = (l & 3) * 8;          // 0,8,16,24

  f32x4 acc[4][JN] = {};

  const bf16_t* pa = &A[(size_t)(m0 + w * 16 + srow) * K + skc];
  const bf16_t* pb = &Bt[(size_t)(n0 + w * 16 + srow) * K + skc];

  for (int k0 = 0; k0 < K; k0 += 32) {
    gll16(pa + k0, &As[(w * 16) * 32]);
    gll16(pa + (size_t)64 * K + k0, &As[(64 + w * 16) * 32]);
    gll16(pb + k0, &Bs[(w * 16) * 32]);
    if constexpr (TN == 128) {
      gll16(pb + (size_t)64 * K + k0, &Bs[(64 + w * 16) * 32]);
    }
    __syncthreads();
    bf16x8 af[4], bfr[JN];
#pragma unroll
    for (int i = 0; i < 4; ++i)
      af[i] = *(const bf16x8*)&As[(wr + i * 16 + r16) * 32 + h * 8];
#pragma unroll
    for (int j = 0; j < JN; ++j)
      bfr[j] = *(const bf16x8*)&Bs[(wc + j * 16 + r16) * 32 + h * 8];
#pragma unroll
    for (int i = 0; i < 4; ++i)
#pragma unroll
      for (int j = 0; j < JN; ++j)
        acc[i][j] = __builtin_amdgcn_mfma_f32_16x16x32_bf16(af[i], bfr[j], acc[i][j], 0, 0, 0);
    __syncthreads();
  }

#pragma unroll
  for (int i = 0; i < 4; ++i)
#pragma unroll
    for (int j = 0; j < JN; ++j)
#pragma unroll
      for (int r = 0; r < 4; ++r) {
        int row = m0 + wr + i * 16 + h * 4 + r;
        int col = n0 + wc + j * 16 + r16;
        if (col < N) {
          float vv = acc[i][j][r];
          size_t idx = (size_t)row * N + col;
          if (OUTMODE == 0) Cf[idx] = vv;
          else if (OUTMODE == 1) Cb[idx] = (bf16_t)vv;
          else if (OUTMODE == 2) Cf[idx] += vv;
          else {
            float g = Cf[idx];
            float s = g / (1.f + expf(-g));
            Cb[idx] = (bf16_t)(s * vv);
          }
        }
      }
}

// ---------------- RoPE (f32 q,k -> bf16 q,k) ----------------
__global__ __launch_bounds__(256) void k_rope(const float* __restrict__ qf,
                                              const float* __restrict__ kf,
                                              bf16_t* __restrict__ qb,
                                              bf16_t* __restrict__ kb) {
  int id = blockIdx.x * 256 + threadIdx.x;   // SEQ*NH*32 total
  int i = id & 31;
  int head = (id >> 5) & 15;
  int s = id >> 9;
  float ang = (float)s * powf(10000.f, -(float)i * (1.f / 32.f));
  float sn, cs;
  sincosf(ang, &sn, &cs);
  size_t base = (size_t)s * DIM + head * HD + i;
  float q0 = qf[base], q1 = qf[base + 32];
  qb[base]      = (bf16_t)(q0 * cs - q1 * sn);
  qb[base + 32] = (bf16_t)(q1 * cs + q0 * sn);
  float k0 = kf[base], k1 = kf[base + 32];
  kb[base]      = (bf16_t)(k0 * cs - k1 * sn);
  kb[base + 32] = (bf16_t)(k1 * cs + k0 * sn);
}

// ---------------- flash attention: 4 waves/block, 64 q-rows/block, K-chunk 64 ----
__global__ __launch_bounds__(256) void k_attn4(const bf16_t* __restrict__ qb,
                                               const bf16_t* __restrict__ kb,
                                               const bf16_t* __restrict__ vb,
                                               bf16_t* __restrict__ ao) {
  __shared__ bf16_t Ks[64][72];       // K chunk: [key][dh], +8 pad
  __shared__ bf16_t Vt[64][72];       // V chunk transposed: [dh][key]
  __shared__ bf16_t Pl[4][16][72];    // per-wave P: [qrow][key]
  const int qt = blockIdx.x;
  const int head = blockIdx.y;
  const int t = threadIdx.x;
  const int w = t >> 6, l = t & 63;
  const int h = l >> 4, r16 = l & 15;
  const int q0 = qt * 64 + w * 16;    // this wave's first q row
  const size_t hoff = (size_t)head * HD;

  bf16x8 aq[2];
#pragma unroll
  for (int c = 0; c < 2; ++c)
    aq[c] = *(const bf16x8*)&qb[(size_t)(q0 + r16) * DIM + hoff + c * 32 + h * 8];

  f32x4 o[4] = {};
  float mrow[4], lrow[4];
#pragma unroll
  for (int r = 0; r < 4; ++r) { mrow[r] = -1e30f; lrow[r] = 0.f; }

  const int srow = t >> 2;            // 0..63 staging row
  const int ssg  = (t & 3) * 8;       // 0,8,16,24

  const int kend = qt * 64 + 63;
  for (int k0 = 0; k0 <= kend; k0 += 64) {
    // ---- cooperative stage: K direct, V transposed ----
#pragma unroll
    for (int it = 0; it < 2; ++it) {
      bf16x8 kv = *(const bf16x8*)&kb[(size_t)(k0 + srow) * DIM + hoff + ssg + it * 32];
      *(bf16x8*)&Ks[srow][ssg + it * 32] = kv;
    }
#pragma unroll
    for (int it = 0; it < 2; ++it) {
      bf16x8 vv = *(const bf16x8*)&vb[(size_t)(k0 + srow) * DIM + hoff + ssg + it * 32];
#pragma unroll
      for (int j = 0; j < 8; ++j) Vt[ssg + it * 32 + j][srow] = vv[j];
    }
    __syncthreads();

    // ---- scores: 4 col-tiles of 16 keys ----
    f32x4 sc[4];
#pragma unroll
    for (int tc = 0; tc < 4; ++tc) {
      f32x4 z = {};
      bf16x8 b0 = *(const bf16x8*)&Ks[tc * 16 + r16][h * 8];
      bf16x8 b1 = *(const bf16x8*)&Ks[tc * 16 + r16][32 + h * 8];
      z = __builtin_amdgcn_mfma_f32_16x16x32_bf16(aq[0], b0, z, 0, 0, 0);
      z = __builtin_amdgcn_mfma_f32_16x16x32_bf16(aq[1], b1, z, 0, 0, 0);
      sc[tc] = z;
    }
    // ---- mask + scale ----
#pragma unroll
    for (int tc = 0; tc < 4; ++tc)
#pragma unroll
      for (int r = 0; r < 4; ++r) {
        int row = q0 + h * 4 + r;
        int col = k0 + tc * 16 + r16;
        float v = sc[tc][r] * 0.125f;
        if (col > row) v = -1e30f;
        sc[tc][r] = v;
      }
    // ---- online softmax (per row r, 16-lane reduce within h-group) ----
#pragma unroll
    for (int r = 0; r < 4; ++r) {
      float mx = fmaxf(fmaxf(sc[0][r], sc[1][r]), fmaxf(sc[2][r], sc[3][r]));
#pragma unroll
      for (int d = 1; d < 16; d <<= 1) mx = fmaxf(mx, __shfl_xor(mx, d));
      float mnew = fmaxf(mrow[r], mx);
      float alpha = expf(mrow[r] - mnew);
      float p0 = expf(sc[0][r] - mnew);
      float p1 = expf(sc[1][r] - mnew);
      float p2 = expf(sc[2][r] - mnew);
      float p3 = expf(sc[3][r] - mnew);
      float ssum = (p0 + p1) + (p2 + p3);
#pragma unroll
      for (int d = 1; d < 16; d <<= 1) ssum += __shfl_xor(ssum, d);
      lrow[r] = lrow[r] * alpha + ssum;
      mrow[r] = mnew;
#pragma unroll
      for (int ct = 0; ct < 4; ++ct) o[ct][r] *= alpha;
      Pl[w][h * 4 + r][r16]      = (bf16_t)p0;
      Pl[w][h * 4 + r][16 + r16] = (bf16_t)p1;
      Pl[w][h * 4 + r][32 + r16] = (bf16_t)p2;
      Pl[w][h * 4 + r][48 + r16] = (bf16_t)p3;
    }
    // ---- PV: k-dim 64 = 2 slices of 32 (wave-local LDS dep, no barrier needed) ----
    bf16x8 pa0 = *(const bf16x8*)&Pl[w][r16][h * 8];
    bf16x8 pa1 = *(const bf16x8*)&Pl[w][r16][32 + h * 8];
#pragma unroll
    for (int ct = 0; ct < 4; ++ct) {
      bf16x8 v0 = *(const bf16x8*)&Vt[ct * 16 + r16][h * 8];
      bf16x8 v1 = *(const bf16x8*)&Vt[ct * 16 + r16][32 + h * 8];
      o[ct] = __builtin_amdgcn_mfma_f32_16x16x32_bf16(pa0, v0, o[ct], 0, 0, 0);
      o[ct] = __builtin_amdgcn_mfma_f32_16x16x32_bf16(pa1, v1, o[ct], 0, 0, 0);
    }
    __syncthreads();
  }
#pragma unroll
  for (int ct = 0; ct < 4; ++ct)
#pragma unroll
    for (int r = 0; r < 4; ++r) {
      int row = q0 + h * 4 + r;
      float vv = o[ct][r] / lrow[r];
      ao[(size_t)row * DIM + hoff + ct * 16 + r16] = (bf16_t)vv;
    }
}

extern "C" void kernel_launch(void* const* d_in, const int* in_sizes, int n_in,
                              void* d_out, int out_size, void* d_ws, size_t ws_size,
                              hipStream_t stream) {
  const int*   ids  = (const int*)d_in[0];
  const float* temb = (const float*)d_in[1];
  const float* Wq   = (const float*)d_in[2];
  const float* Wk   = (const float*)d_in[3];
  const float* Wv   = (const float*)d_in[4];
  const float* Wo   = (const float*)d_in[5];
  const float* ln1s = (const float*)d_in[6];
  const float* ln1b = (const float*)d_in[7];
  const float* ln2s = (const float*)d_in[8];
  const float* ln2b = (const float*)d_in[9];
  const float* w1   = (const float*)d_in[10];
  const float* w2   = (const float*)d_in[11];
  const float* w3   = (const float*)d_in[12];
  const float* lnfs = (const float*)d_in[13];
  const float* lnfb = (const float*)d_in[14];
  const float* lmh  = (const float*)d_in[15];
  float* out = (float*)d_out;

  char* p = (char*)d_ws;
  size_t used = 0;
  auto alloc = [&](size_t bytes) {
    void* r = (void*)p;
    size_t a = (bytes + 255) & ~(size_t)255;
    p += a; used += a;
    return r;
  };
  // activations
  float*  x     = (float*)alloc((size_t)SEQ * DIM * 4);
  bf16_t* hb    = (bf16_t*)alloc((size_t)SEQ * DIM * 2);
  float*  qf    = (float*)alloc((size_t)SEQ * DIM * 4);
  float*  kf    = (float*)alloc((size_t)SEQ * DIM * 4);
  bf16_t* qb2   = (bf16_t*)alloc((size_t)SEQ * DIM * 2);
  bf16_t* kb2   = (bf16_t*)alloc((size_t)SEQ * DIM * 2);
  bf16_t* vb2   = (bf16_t*)alloc((size_t)SEQ * DIM * 2);
  bf16_t* aob   = (bf16_t*)alloc((size_t)SEQ * DIM * 2);
  float*  g1    = (float*)alloc((size_t)SEQ * FF * 4);
  bf16_t* gateb = (bf16_t*)alloc((size_t)SEQ * FF * 2);

  const size_t szDD = (size_t)DIM * DIM;
  const size_t szDF = (size_t)DIM * FF;
  const size_t wt_bytes = (4 * (size_t)NL * szDD + 3 * (size_t)NL * szDF + (size_t)VOCP * DIM) * 2;
  const bool bigws = (ws_size >= used + wt_bytes + (1u << 20));

  bf16_t *bWq, *bWk, *bWv, *bWo, *bw1, *bw2, *bw3, *blm, *wscratch = nullptr;
  if (bigws) {
    bWq = (bf16_t*)alloc(NL * szDD * 2);
    bWk = (bf16_t*)alloc(NL * szDD * 2);
    bWv = (bf16_t*)alloc(NL * szDD * 2);
    bWo = (bf16_t*)alloc(NL * szDD * 2);
    bw1 = (bf16_t*)alloc(NL * szDF * 2);
    bw2 = (bf16_t*)alloc(NL * szDF * 2);
    bw3 = (bf16_t*)alloc(NL * szDF * 2);
    blm = (bf16_t*)alloc((size_t)VOCP * DIM * 2);
  } else {
    wscratch = (bf16_t*)alloc(szDF * 2);
    bWq = bWk = bWv = bWo = bw1 = bw2 = bw3 = blm = wscratch;
  }

  auto cvt = [&](const float* src, bf16_t* dst, int K_, int N_, int Npad_, int nz) {
    dim3 g(Npad_ / 64, K_ / 64, nz);
    k_cvt_t<<<g, 256, 0, stream>>>(src, dst, K_, N_, Npad_);
  };

  if (bigws) {
    cvt(Wq, bWq, DIM, DIM, DIM, NL);
    cvt(Wk, bWk, DIM, DIM, DIM, NL);
    cvt(Wv, bWv, DIM, DIM, DIM, NL);
    cvt(Wo, bWo, DIM, DIM, DIM, NL);
    cvt(w1, bw1, DIM, FF, FF, NL);
    cvt(w3, bw3, DIM, FF, FF, NL);
    cvt(w2, bw2, FF, DIM, DIM, NL);
    cvt(lmh, blm, DIM, VOC, VOCP, 1);
  }
  auto wp = [&](bf16_t* big, const float* src, int lyr, int K_, int N_, int Npad_) -> bf16_t* {
    if (bigws) return big + (size_t)lyr * Npad_ * K_;
    cvt(src + (size_t)lyr * K_ * N_, wscratch, K_, N_, Npad_, 1);
    return wscratch;
  };

  k_embed<<<SEQ, 256, 0, stream>>>(ids, temb, x);

  dim3 gDD(DIM / 64, SEQ / 128);
  dim3 gDF(FF / 128, SEQ / 128);
  dim3 gLM(VOCP / 64, SEQ / 128);
  dim3 gAt(SEQ / 64, NH);

  for (int l = 0; l < NL; ++l) {
    k_ln<<<SEQ, 64, 0, stream>>>(x, ln1s + (size_t)l * DIM, ln1b + (size_t)l * DIM, hb);
    k_gemm2<64, 0><<<gDD, 256, 0, stream>>>(hb, wp(bWq, Wq, l, DIM, DIM, DIM), qf, nullptr, SEQ, DIM, DIM);
    k_gemm2<64, 0><<<gDD, 256, 0, stream>>>(hb, wp(bWk, Wk, l, DIM, DIM, DIM), kf, nullptr, SEQ, DIM, DIM);
    k_gemm2<64, 1><<<gDD, 256, 0, stream>>>(hb, wp(bWv, Wv, l, DIM, DIM, DIM), nullptr, vb2, SEQ, DIM, DIM);
    k_rope<<<(SEQ * NH * 32) / 256, 256, 0, stream>>>(qf, kf, qb2, kb2);
    k_attn4<<<gAt, 256, 0, stream>>>(qb2, kb2, vb2, aob);
    k_gemm2<64, 2><<<gDD, 256, 0, stream>>>(aob, wp(bWo, Wo, l, DIM, DIM, DIM), x, nullptr, SEQ, DIM, DIM);
    k_ln<<<SEQ, 64, 0, stream>>>(x, ln2s + (size_t)l * DIM, ln2b + (size_t)l * DIM, hb);
    k_gemm2<128, 0><<<gDF, 256, 0, stream>>>(hb, wp(bw1, w1, l, DIM, FF, FF), g1, nullptr, SEQ, FF, DIM);
    k_gemm2<128, 3><<<gDF, 256, 0, stream>>>(hb, wp(bw3, w3, l, DIM, FF, FF), g1, gateb, SEQ, FF, DIM);
    k_gemm2<64, 2><<<gDD, 256, 0, stream>>>(gateb, wp(bw2, w2, l, FF, DIM, DIM), x, nullptr, SEQ, DIM, FF);
  }
  k_ln<<<SEQ, 64, 0, stream>>>(x, lnfs, lnfb, hb);
  k_gemm2<64, 0><<<gLM, 256, 0, stream>>>(hb, bigws ? blm : wp(blm, lmh, 0, DIM, VOC, VOCP), out, nullptr, SEQ, VOC, DIM);
}

// Round 6
// 3862.359 us; speedup vs baseline: 3.9266x; 1.2280x over previous
//
#include <hip/hip_runtime.h>
#include <math.h>

// ---- problem constants ----
constexpr int SEQ = 2048;
constexpr int DIM = 1024;
constexpr int NH  = 16;
constexpr int HD  = 64;
constexpr int FF  = 4096;
constexpr int NL  = 12;
constexpr int VOC = 1400;
constexpr int VOCP = 1408;   // padded to 64

typedef __bf16 bf16_t;
typedef __bf16 bf16x8 __attribute__((ext_vector_type(8)));
typedef float  f32x4  __attribute__((ext_vector_type(4)));

typedef __attribute__((address_space(1))) const void GV;
typedef __attribute__((address_space(3))) void LV;

__device__ __forceinline__ void gll16(const bf16_t* g, bf16_t* l) {
  __builtin_amdgcn_global_load_lds((GV*)g, (LV*)l, 16, 0, 0);
}

// ---------------- embedding gather ----------------
__global__ __launch_bounds__(256) void k_embed(const int* __restrict__ ids,
                                               const float* __restrict__ emb,
                                               float* __restrict__ x) {
  int s = blockIdx.x;
  int d = threadIdx.x * 4;
  const float4 v = *(const float4*)&emb[(size_t)ids[s] * DIM + d];
  *(float4*)&x[(size_t)s * DIM + d] = v;
}

// ---------------- RoPE cos/sin table: [s][i], i = freq idx 0..31 ----------------
__global__ __launch_bounds__(256) void k_rtab(float* __restrict__ ct,
                                              float* __restrict__ st) {
  int id = blockIdx.x * 256 + threadIdx.x;   // SEQ*32
  int i = id & 31;
  int s = id >> 5;
  float ang = (float)s * powf(10000.f, -(float)i * (1.f / 32.f));
  float sn, cs;
  sincosf(ang, &sn, &cs);
  ct[id] = cs;
  st[id] = sn;
}

// ---------------- layernorm (f32 in -> bf16 out), 1 wave per row ----------------
__global__ __launch_bounds__(64) void k_ln(const float* __restrict__ x,
                                           const float* __restrict__ sc,
                                           const float* __restrict__ bi,
                                           bf16_t* __restrict__ out) {
  int s = blockIdx.x;
  int l = threadIdx.x;
  const float* xr = x + (size_t)s * DIM;
  float4 v[4];
  float sum = 0.f, sq = 0.f;
#pragma unroll
  for (int i = 0; i < 4; ++i) {
    v[i] = *(const float4*)&xr[i * 256 + l * 4];
#pragma unroll
    for (int j = 0; j < 4; ++j) { sum += v[i][j]; sq += v[i][j] * v[i][j]; }
  }
#pragma unroll
  for (int d = 1; d < 64; d <<= 1) {
    sum += __shfl_xor(sum, d);
    sq  += __shfl_xor(sq, d);
  }
  float mean = sum * (1.f / DIM);
  float var  = sq * (1.f / DIM) - mean * mean;
  float inv  = rsqrtf(var + 1e-5f);
#pragma unroll
  for (int i = 0; i < 4; ++i) {
    int off = i * 256 + l * 4;
    float4 scv = *(const float4*)&sc[off];
    float4 biv = *(const float4*)&bi[off];
#pragma unroll
    for (int j = 0; j < 4; ++j) {
      float o = (v[i][j] - mean) * inv * scv[j] + biv[j];
      out[(size_t)s * DIM + off + j] = (bf16_t)o;
    }
  }
}

// ------- weight convert + transpose: src[K][N] f32 -> dst[Npad][K] bf16 -------
// blockIdx.z = matrix idx; dst layer stride = dstride elems. Zero-fills n >= N.
__global__ __launch_bounds__(256) void k_cvt_t(const float* __restrict__ src,
                                               bf16_t* __restrict__ dst,
                                               int K_, int N_, int Npad_,
                                               size_t dstride) {
  __shared__ bf16_t T[64][66];
  const int k0 = blockIdx.y * 64;
  const int n0 = blockIdx.x * 64;
  const size_t so = (size_t)blockIdx.z * K_ * N_;
  const size_t dof = (size_t)blockIdx.z * dstride;
  const int t = threadIdx.x;
  const int kk = t >> 4;
  const int nn = (t & 15) * 4;
#pragma unroll
  for (int it = 0; it < 4; ++it) {
    int krow = kk + it * 16;
    float4 v = {0.f, 0.f, 0.f, 0.f};
    if (n0 + nn < N_) v = *(const float4*)&src[so + (size_t)(k0 + krow) * N_ + n0 + nn];
#pragma unroll
    for (int q = 0; q < 4; ++q) T[nn + q][krow] = (bf16_t)v[q];
  }
  __syncthreads();
#pragma unroll
  for (int it = 0; it < 4; ++it) {
    int c = it * 256 + t;
    int nr = c >> 4;
    int kc = (c & 15) * 4;
    ushort4 o = *(const ushort4*)&T[nr][kc];
    *(ushort4*)&dst[dof + (size_t)(n0 + nr) * K_ + k0 + kc] = o;
  }
}

// ---------------- GEMM (m97 structure): C[M,N] = A[M,K] * Bt[N][K], bf16 MFMA ----
// tile 128 x TN, BK=32, 4 waves (2x2).
// OUTMODE 0: f32 store | 2: f32 += | 4: fused QKV(+RoPE) | 5: fused w1/w3 store
template <int TN, int OUTMODE>
__global__ __launch_bounds__(256) void k_gemm2(const bf16_t* __restrict__ A,
                                               const bf16_t* __restrict__ Bt,
                                               float* __restrict__ Cf,
                                               bf16_t* __restrict__ Cb,
                                               bf16_t* __restrict__ aux1,
                                               bf16_t* __restrict__ aux2,
                                               const float* __restrict__ ct,
                                               const float* __restrict__ st,
                                               int M, int N, int K) {
  constexpr int JN = TN / 32;            // B frags per wave
  __shared__ bf16_t As[128 * 32];
  __shared__ bf16_t Bs[TN * 32];
  const int t = threadIdx.x;
  const int w = t >> 6, l = t & 63;
  const int h = l >> 4, r16 = l & 15;
  const int m0 = blockIdx.y * 128, n0 = blockIdx.x * TN;
  const int wr = (w >> 1) * 64;
  const int wc = (w & 1) * (TN / 2);
  const int srow = l >> 2;               // 0..15
  const int skc  = (l & 3) * 8;          // 0,8,16,24

  f32x4 acc[4][JN] = {};

  const bf16_t* pa = &A[(size_t)(m0 + w * 16 + srow) * K + skc];
  const bf16_t* pb = &Bt[(size_t)(n0 + w * 16 + srow) * K + skc];

  for (int k0 = 0; k0 < K; k0 += 32) {
    gll16(pa + k0, &As[(w * 16) * 32]);
    gll16(pa + (size_t)64 * K + k0, &As[(64 + w * 16) * 32]);
    gll16(pb + k0, &Bs[(w * 16) * 32]);
    if constexpr (TN == 128) {
      gll16(pb + (size_t)64 * K + k0, &Bs[(64 + w * 16) * 32]);
    }
    __syncthreads();
    bf16x8 af[4], bfr[JN];
#pragma unroll
    for (int i = 0; i < 4; ++i)
      af[i] = *(const bf16x8*)&As[(wr + i * 16 + r16) * 32 + h * 8];
#pragma unroll
    for (int j = 0; j < JN; ++j)
      bfr[j] = *(const bf16x8*)&Bs[(wc + j * 16 + r16) * 32 + h * 8];
#pragma unroll
    for (int i = 0; i < 4; ++i)
#pragma unroll
      for (int j = 0; j < JN; ++j)
        acc[i][j] = __builtin_amdgcn_mfma_f32_16x16x32_bf16(af[i], bfr[j], acc[i][j], 0, 0, 0);
    __syncthreads();
  }

  if constexpr (OUTMODE == 4) {
    // fused QKV epilogue: region by n0 (0..1023 q, 1024..2047 k, 2048..3071 v)
    const int reg = n0 >> 10;
    const int cbase = (n0 & 1023) + wc;
    if (reg == 2) {
#pragma unroll
      for (int i = 0; i < 4; ++i)
#pragma unroll
        for (int j = 0; j < JN; ++j)
#pragma unroll
          for (int r = 0; r < 4; ++r) {
            int row = m0 + wr + i * 16 + h * 4 + r;
            Cb[(size_t)row * DIM + cbase + j * 16 + r16] = (bf16_t)acc[i][j][r];
          }
    } else {
      bf16_t* dst = reg ? aux2 : aux1;
#pragma unroll
      for (int i = 0; i < 4; ++i)
#pragma unroll
        for (int r = 0; r < 4; ++r) {
          int row = m0 + wr + i * 16 + h * 4 + r;
          float c0 = ct[row * 32 + r16],      s0 = st[row * 32 + r16];
          float c1 = ct[row * 32 + 16 + r16], s1 = st[row * 32 + 16 + r16];
          float lo0 = acc[i][0][r], hi0 = acc[i][2][r];
          float lo1 = acc[i][1][r], hi1 = acc[i][3][r];
          size_t rb = (size_t)row * DIM + cbase;
          dst[rb + r16]      = (bf16_t)(lo0 * c0 - hi0 * s0);
          dst[rb + 32 + r16] = (bf16_t)(hi0 * c0 + lo0 * s0);
          dst[rb + 16 + r16] = (bf16_t)(lo1 * c1 - hi1 * s1);
          dst[rb + 48 + r16] = (bf16_t)(hi1 * c1 + lo1 * s1);
        }
    }
  } else if constexpr (OUTMODE == 5) {
    const int reg = n0 >> 12;              // 0: w1 -> aux1, 1: w3 -> aux2
    bf16_t* dst = reg ? aux2 : aux1;
    const int cbase = (n0 & 4095) + wc;
#pragma unroll
    for (int i = 0; i < 4; ++i)
#pragma unroll
      for (int j = 0; j < JN; ++j)
#pragma unroll
        for (int r = 0; r < 4; ++r) {
          int row = m0 + wr + i * 16 + h * 4 + r;
          dst[(size_t)row * FF + cbase + j * 16 + r16] = (bf16_t)acc[i][j][r];
        }
  } else {
#pragma unroll
    for (int i = 0; i < 4; ++i)
#pragma unroll
      for (int j = 0; j < JN; ++j)
#pragma unroll
        for (int r = 0; r < 4; ++r) {
          int row = m0 + wr + i * 16 + h * 4 + r;
          int col = n0 + wc + j * 16 + r16;
          if (col < N) {
            float vv = acc[i][j][r];
            size_t idx = (size_t)row * N + col;
            if (OUTMODE == 0) Cf[idx] = vv;
            else Cf[idx] += vv;
          }
        }
  }
}

// ---------------- flash attention: 4 waves/block, swapped-QK layout ----------------
// D = K x Q: lane holds q = q0 + (l&15) fixed; keys vary -> softmax reduce is
// 2 shuffles (xor 16, 32). Waves skip fully-masked chunks.
__global__ __launch_bounds__(256) void k_attn4(const bf16_t* __restrict__ qb,
                                               const bf16_t* __restrict__ kb,
                                               const bf16_t* __restrict__ vb,
                                               bf16_t* __restrict__ ao) {
  __shared__ bf16_t Ks[64][72];       // K chunk: [key][dh]
  __shared__ bf16_t Vt[64][72];       // V chunk transposed: [dh][key]
  __shared__ bf16_t Pl[4][16][72];    // per-wave P: [qrow][key]
  const int qt = blockIdx.x;
  const int head = blockIdx.y;
  const int t = threadIdx.x;
  const int w = t >> 6, l = t & 63;
  const int h = l >> 4, r16 = l & 15;
  const int q0 = qt * 64 + w * 16;    // this wave's first q row
  const int q_abs = q0 + r16;         // this lane's q row (softmax axis)
  const size_t hoff = (size_t)head * HD;

  bf16x8 aq[2];
#pragma unroll
  for (int c = 0; c < 2; ++c)
    aq[c] = *(const bf16x8*)&qb[(size_t)(q0 + r16) * DIM + hoff + c * 32 + h * 8];

  f32x4 o[4] = {};
  float mrun = -1e30f, lrun = 0.f;

  const int srow = t >> 2;            // 0..63 staging row
  const int ssg  = (t & 3) * 8;       // 0,8,16,24

  const int kend = qt * 64 + 63;
  for (int k0 = 0; k0 <= kend; k0 += 64) {
    // ---- cooperative stage: K direct, V transposed ----
#pragma unroll
    for (int it = 0; it < 2; ++it) {
      bf16x8 kv = *(const bf16x8*)&kb[(size_t)(k0 + srow) * DIM + hoff + ssg + it * 32];
      *(bf16x8*)&Ks[srow][ssg + it * 32] = kv;
    }
#pragma unroll
    for (int it = 0; it < 2; ++it) {
      bf16x8 vv = *(const bf16x8*)&vb[(size_t)(k0 + srow) * DIM + hoff + ssg + it * 32];
#pragma unroll
      for (int j = 0; j < 8; ++j) Vt[ssg + it * 32 + j][srow] = vv[j];
    }
    __syncthreads();

    if (k0 <= q0 + 15) {              // wave-uniform: skip fully-masked chunks
      // ---- scores transposed: D[key][q] ----
      f32x4 sc[4];
      __builtin_amdgcn_s_setprio(1);
#pragma unroll
      for (int tc = 0; tc < 4; ++tc) {
        f32x4 z = {};
        bf16x8 a0 = *(const bf16x8*)&Ks[tc * 16 + r16][h * 8];
        bf16x8 a1 = *(const bf16x8*)&Ks[tc * 16 + r16][32 + h * 8];
        z = __builtin_amdgcn_mfma_f32_16x16x32_bf16(a0, aq[0], z, 0, 0, 0);
        z = __builtin_amdgcn_mfma_f32_16x16x32_bf16(a1, aq[1], z, 0, 0, 0);
        sc[tc] = z;
      }
      __builtin_amdgcn_s_setprio(0);
      // ---- mask + scale; per-lane max over 16 keys ----
      float pmax = -1e30f;
#pragma unroll
      for (int tc = 0; tc < 4; ++tc)
#pragma unroll
        for (int r = 0; r < 4; ++r) {
          int key = k0 + tc * 16 + h * 4 + r;
          float v = sc[tc][r] * 0.125f;
          if (key > q_abs) v = -1e30f;
          sc[tc][r] = v;
          pmax = fmaxf(pmax, v);
        }
      pmax = fmaxf(pmax, __shfl_xor(pmax, 16));
      pmax = fmaxf(pmax, __shfl_xor(pmax, 32));
      float mnew = fmaxf(mrun, pmax);
      float alpha = expf(mrun - mnew);
      mrun = mnew;
      float ssum = 0.f;
#pragma unroll
      for (int tc = 0; tc < 4; ++tc)
#pragma unroll
        for (int r = 0; r < 4; ++r) {
          float pv = expf(sc[tc][r] - mnew);
          sc[tc][r] = pv;
          ssum += pv;
        }
      ssum += __shfl_xor(ssum, 16);
      ssum += __shfl_xor(ssum, 32);
      lrun = lrun * alpha + ssum;
      // ---- write P^T to LDS: Pl[q][key] ----
#pragma unroll
      for (int tc = 0; tc < 4; ++tc)
#pragma unroll
        for (int r = 0; r < 4; ++r)
          Pl[w][r16][tc * 16 + h * 4 + r] = (bf16_t)sc[tc][r];
      // ---- rescale o: alpha for o-row q=h*4+r lives in lane h*4+r ----
      float ar[4];
#pragma unroll
      for (int r = 0; r < 4; ++r) ar[r] = __shfl(alpha, h * 4 + r);
#pragma unroll
      for (int cti = 0; cti < 4; ++cti)
#pragma unroll
        for (int r = 0; r < 4; ++r) o[cti][r] *= ar[r];
      // ---- PV ----
      bf16x8 pa0 = *(const bf16x8*)&Pl[w][r16][h * 8];
      bf16x8 pa1 = *(const bf16x8*)&Pl[w][r16][32 + h * 8];
      __builtin_amdgcn_s_setprio(1);
#pragma unroll
      for (int cti = 0; cti < 4; ++cti) {
        bf16x8 v0 = *(const bf16x8*)&Vt[cti * 16 + r16][h * 8];
        bf16x8 v1 = *(const bf16x8*)&Vt[cti * 16 + r16][32 + h * 8];
        o[cti] = __builtin_amdgcn_mfma_f32_16x16x32_bf16(pa0, v0, o[cti], 0, 0, 0);
        o[cti] = __builtin_amdgcn_mfma_f32_16x16x32_bf16(pa1, v1, o[cti], 0, 0, 0);
      }
      __builtin_amdgcn_s_setprio(0);
    }
    __syncthreads();
  }
  float lr[4];
#pragma unroll
  for (int r = 0; r < 4; ++r) lr[r] = __shfl(lrun, h * 4 + r);
#pragma unroll
  for (int cti = 0; cti < 4; ++cti)
#pragma unroll
    for (int r = 0; r < 4; ++r) {
      int row = q0 + h * 4 + r;
      ao[(size_t)row * DIM + hoff + cti * 16 + r16] = (bf16_t)(o[cti][r] / lr[r]);
    }
}

// ---------------- silu(g1) * g3, bf16 in/out, x8 vectorized ----------------
__global__ __launch_bounds__(256) void k_gate(const bf16_t* __restrict__ g1,
                                              const bf16_t* __restrict__ g3,
                                              bf16_t* __restrict__ out, int n8) {
  int i = blockIdx.x * 256 + threadIdx.x;
  if (i < n8) {
    bf16x8 a = ((const bf16x8*)g1)[i];
    bf16x8 b = ((const bf16x8*)g3)[i];
    bf16x8 o;
#pragma unroll
    for (int j = 0; j < 8; ++j) {
      float f = (float)a[j];
      float s = f / (1.f + expf(-f));
      o[j] = (bf16_t)(s * (float)b[j]);
    }
    ((bf16x8*)out)[i] = o;
  }
}

extern "C" void kernel_launch(void* const* d_in, const int* in_sizes, int n_in,
                              void* d_out, int out_size, void* d_ws, size_t ws_size,
                              hipStream_t stream) {
  const int*   ids  = (const int*)d_in[0];
  const float* temb = (const float*)d_in[1];
  const float* Wq   = (const float*)d_in[2];
  const float* Wk   = (const float*)d_in[3];
  const float* Wv   = (const float*)d_in[4];
  const float* Wo   = (const float*)d_in[5];
  const float* ln1s = (const float*)d_in[6];
  const float* ln1b = (const float*)d_in[7];
  const float* ln2s = (const float*)d_in[8];
  const float* ln2b = (const float*)d_in[9];
  const float* w1   = (const float*)d_in[10];
  const float* w2   = (const float*)d_in[11];
  const float* w3   = (const float*)d_in[12];
  const float* lnfs = (const float*)d_in[13];
  const float* lnfb = (const float*)d_in[14];
  const float* lmh  = (const float*)d_in[15];
  float* out = (float*)d_out;

  char* p = (char*)d_ws;
  size_t used = 0;
  auto alloc = [&](size_t bytes) {
    void* r = (void*)p;
    size_t a = (bytes + 255) & ~(size_t)255;
    p += a; used += a;
    return r;
  };
  // activations + tables
  float*  x     = (float*)alloc((size_t)SEQ * DIM * 4);
  bf16_t* hb    = (bf16_t*)alloc((size_t)SEQ * DIM * 2);
  bf16_t* qb2   = (bf16_t*)alloc((size_t)SEQ * DIM * 2);
  bf16_t* kb2   = (bf16_t*)alloc((size_t)SEQ * DIM * 2);
  bf16_t* vb2   = (bf16_t*)alloc((size_t)SEQ * DIM * 2);
  bf16_t* aob   = (bf16_t*)alloc((size_t)SEQ * DIM * 2);
  bf16_t* g1b   = (bf16_t*)alloc((size_t)SEQ * FF * 2);
  bf16_t* g3b   = (bf16_t*)alloc((size_t)SEQ * FF * 2);
  bf16_t* gateb = (bf16_t*)alloc((size_t)SEQ * FF * 2);
  float*  ctab  = (float*)alloc((size_t)SEQ * 32 * 4);
  float*  stab  = (float*)alloc((size_t)SEQ * 32 * 4);

  const size_t szDD = (size_t)DIM * DIM;    // 1M elems
  const size_t szDF = (size_t)DIM * FF;     // 4M elems
  const size_t wt_bytes = ((size_t)NL * (3 * szDD + szDD + 2 * szDF + szDF) + (size_t)VOCP * DIM) * 2;
  const bool bigws = (ws_size >= used + wt_bytes + (1u << 20));

  bf16_t *bQKV, *bWo, *bW13, *bw2, *blm, *wscratch = nullptr;
  if (bigws) {
    bQKV = (bf16_t*)alloc(NL * 3 * szDD * 2);
    bWo  = (bf16_t*)alloc(NL * szDD * 2);
    bW13 = (bf16_t*)alloc(NL * 2 * szDF * 2);
    bw2  = (bf16_t*)alloc(NL * szDF * 2);
    blm  = (bf16_t*)alloc((size_t)VOCP * DIM * 2);
  } else {
    wscratch = (bf16_t*)alloc(2 * szDF * 2);   // enough for fused w13 of one layer
    bQKV = bWo = bW13 = bw2 = blm = wscratch;
  }

  auto cvt = [&](const float* src, bf16_t* dst, int K_, int N_, int Npad_, int nz, size_t dstride) {
    dim3 g(Npad_ / 64, K_ / 64, nz);
    k_cvt_t<<<g, 256, 0, stream>>>(src, dst, K_, N_, Npad_, dstride);
  };

  if (bigws) {
    cvt(Wq, bQKV,             DIM, DIM, DIM, NL, 3 * szDD);
    cvt(Wk, bQKV + szDD,      DIM, DIM, DIM, NL, 3 * szDD);
    cvt(Wv, bQKV + 2 * szDD,  DIM, DIM, DIM, NL, 3 * szDD);
    cvt(Wo, bWo,              DIM, DIM, DIM, NL, szDD);
    cvt(w1, bW13,             DIM, FF,  FF,  NL, 2 * szDF);
    cvt(w3, bW13 + szDF,      DIM, FF,  FF,  NL, 2 * szDF);
    cvt(w2, bw2,              FF,  DIM, DIM, NL, szDF);   // FIX: layer stride szDF (was szDD)
    cvt(lmh, blm,             DIM, VOC, VOCP, 1, 0);
  }
  auto wpQKV = [&](int lyr) -> bf16_t* {
    if (bigws) return bQKV + (size_t)lyr * 3 * szDD;
    cvt(Wq + (size_t)lyr * szDD, wscratch,            DIM, DIM, DIM, 1, 0);
    cvt(Wk + (size_t)lyr * szDD, wscratch + szDD,     DIM, DIM, DIM, 1, 0);
    cvt(Wv + (size_t)lyr * szDD, wscratch + 2 * szDD, DIM, DIM, DIM, 1, 0);
    return wscratch;
  };
  auto wpW13 = [&](int lyr) -> bf16_t* {
    if (bigws) return bW13 + (size_t)lyr * 2 * szDF;
    cvt(w1 + (size_t)lyr * szDF, wscratch,        DIM, FF, FF, 1, 0);
    cvt(w3 + (size_t)lyr * szDF, wscratch + szDF, DIM, FF, FF, 1, 0);
    return wscratch;
  };
  auto wp1 = [&](bf16_t* big, const float* src, int lyr, int K_, int N_, int Npad_) -> bf16_t* {
    if (bigws) return big + (size_t)lyr * Npad_ * K_;
    cvt(src + (size_t)lyr * K_ * N_, wscratch, K_, N_, Npad_, 1, 0);
    return wscratch;
  };

  k_rtab<<<(SEQ * 32) / 256, 256, 0, stream>>>(ctab, stab);
  k_embed<<<SEQ, 256, 0, stream>>>(ids, temb, x);

  dim3 gQKV(3 * DIM / 128, SEQ / 128);   // 24 x 16 = 384
  dim3 gDD(DIM / 64, SEQ / 128);         // 16 x 16 = 256
  dim3 gW13(2 * FF / 128, SEQ / 128);    // 64 x 16 = 1024
  dim3 gLM(VOCP / 64, SEQ / 128);        // 22 x 16 = 352
  dim3 gAt(SEQ / 64, NH);                // 32 x 16 = 512

  for (int l = 0; l < NL; ++l) {
    k_ln<<<SEQ, 64, 0, stream>>>(x, ln1s + (size_t)l * DIM, ln1b + (size_t)l * DIM, hb);
    k_gemm2<128, 4><<<gQKV, 256, 0, stream>>>(hb, wpQKV(l), nullptr, vb2, qb2, kb2,
                                              ctab, stab, SEQ, 3 * DIM, DIM);
    k_attn4<<<gAt, 256, 0, stream>>>(qb2, kb2, vb2, aob);
    k_gemm2<64, 2><<<gDD, 256, 0, stream>>>(aob, wp1(bWo, Wo, l, DIM, DIM, DIM), x, nullptr,
                                            nullptr, nullptr, nullptr, nullptr, SEQ, DIM, DIM);
    k_ln<<<SEQ, 64, 0, stream>>>(x, ln2s + (size_t)l * DIM, ln2b + (size_t)l * DIM, hb);
    k_gemm2<128, 5><<<gW13, 256, 0, stream>>>(hb, wpW13(l), nullptr, nullptr, g1b, g3b,
                                              nullptr, nullptr, SEQ, 2 * FF, DIM);
    k_gate<<<(SEQ * FF / 8 + 255) / 256, 256, 0, stream>>>(g1b, g3b, gateb, SEQ * FF / 8);
    k_gemm2<64, 2><<<gDD, 256, 0, stream>>>(gateb, wp1(bw2, w2, l, FF, DIM, DIM), x, nullptr,
                                            nullptr, nullptr, nullptr, nullptr, SEQ, DIM, FF);
  }
  k_ln<<<SEQ, 64, 0, stream>>>(x, lnfs, lnfb, hb);
  k_gemm2<64, 0><<<gLM, 256, 0, stream>>>(hb, bigws ? blm : wp1(blm, lmh, 0, DIM, VOC, VOCP),
                                          out, nullptr, nullptr, nullptr, nullptr, nullptr,
                                          SEQ, VOC, DIM);
}

// Round 7
// 3721.146 us; speedup vs baseline: 4.0756x; 1.0379x over previous
//
#include <hip/hip_runtime.h>
#include <math.h>

// ---- problem constants ----
constexpr int SEQ = 2048;
constexpr int DIM = 1024;
constexpr int NH  = 16;
constexpr int HD  = 64;
constexpr int FF  = 4096;
constexpr int NL  = 12;
constexpr int VOC = 1400;
constexpr int VOCP = 1408;   // padded to 64

typedef __bf16 bf16_t;
typedef __bf16 bf16x8 __attribute__((ext_vector_type(8)));
typedef float  f32x4  __attribute__((ext_vector_type(4)));

typedef __attribute__((address_space(1))) const void GV;
typedef __attribute__((address_space(3))) void LV;

__device__ __forceinline__ void gll16(const bf16_t* g, bf16_t* l) {
  __builtin_amdgcn_global_load_lds((GV*)g, (LV*)l, 16, 0, 0);
}

// ---------------- embedding gather ----------------
__global__ __launch_bounds__(256) void k_embed(const int* __restrict__ ids,
                                               const float* __restrict__ emb,
                                               float* __restrict__ x) {
  int s = blockIdx.x;
  int d = threadIdx.x * 4;
  const float4 v = *(const float4*)&emb[(size_t)ids[s] * DIM + d];
  *(float4*)&x[(size_t)s * DIM + d] = v;
}

// ---------------- RoPE cos/sin table: [s][i], i = freq idx 0..31 ----------------
__global__ __launch_bounds__(256) void k_rtab(float* __restrict__ ct,
                                              float* __restrict__ st) {
  int id = blockIdx.x * 256 + threadIdx.x;   // SEQ*32
  int i = id & 31;
  int s = id >> 5;
  float ang = (float)s * powf(10000.f, -(float)i * (1.f / 32.f));
  float sn, cs;
  sincosf(ang, &sn, &cs);
  ct[id] = cs;
  st[id] = sn;
}

// ------- layernorm (f32 in -> bf16 out), 4 rows/block, 1 wave per row -------
__global__ __launch_bounds__(256) void k_ln(const float* __restrict__ x,
                                            const float* __restrict__ sc,
                                            const float* __restrict__ bi,
                                            bf16_t* __restrict__ out) {
  int s = blockIdx.x * 4 + (threadIdx.x >> 6);
  int l = threadIdx.x & 63;
  const float* xr = x + (size_t)s * DIM;
  float4 v[4];
  float sum = 0.f, sq = 0.f;
#pragma unroll
  for (int i = 0; i < 4; ++i) {
    v[i] = *(const float4*)&xr[i * 256 + l * 4];
#pragma unroll
    for (int j = 0; j < 4; ++j) { sum += v[i][j]; sq += v[i][j] * v[i][j]; }
  }
#pragma unroll
  for (int d = 1; d < 64; d <<= 1) {
    sum += __shfl_xor(sum, d);
    sq  += __shfl_xor(sq, d);
  }
  float mean = sum * (1.f / DIM);
  float var  = sq * (1.f / DIM) - mean * mean;
  float inv  = rsqrtf(var + 1e-5f);
#pragma unroll
  for (int i = 0; i < 4; ++i) {
    int off = i * 256 + l * 4;
    float4 scv = *(const float4*)&sc[off];
    float4 biv = *(const float4*)&bi[off];
#pragma unroll
    for (int j = 0; j < 4; ++j) {
      float o = (v[i][j] - mean) * inv * scv[j] + biv[j];
      out[(size_t)s * DIM + off + j] = (bf16_t)o;
    }
  }
}

// ------- weight convert + transpose: src[K][N] f32 -> dst[Npad][K] bf16 -------
// blockIdx.z = matrix idx; dst layer stride = dstride elems. Zero-fills n >= N.
__global__ __launch_bounds__(256) void k_cvt_t(const float* __restrict__ src,
                                               bf16_t* __restrict__ dst,
                                               int K_, int N_, int Npad_,
                                               size_t dstride) {
  __shared__ bf16_t T[64][66];
  const int k0 = blockIdx.y * 64;
  const int n0 = blockIdx.x * 64;
  const size_t so = (size_t)blockIdx.z * K_ * N_;
  const size_t dof = (size_t)blockIdx.z * dstride;
  const int t = threadIdx.x;
  const int kk = t >> 4;
  const int nn = (t & 15) * 4;
#pragma unroll
  for (int it = 0; it < 4; ++it) {
    int krow = kk + it * 16;
    float4 v = {0.f, 0.f, 0.f, 0.f};
    if (n0 + nn < N_) v = *(const float4*)&src[so + (size_t)(k0 + krow) * N_ + n0 + nn];
#pragma unroll
    for (int q = 0; q < 4; ++q) T[nn + q][krow] = (bf16_t)v[q];
  }
  __syncthreads();
#pragma unroll
  for (int it = 0; it < 4; ++it) {
    int c = it * 256 + t;
    int nr = c >> 4;
    int kc = (c & 15) * 4;
    ushort4 o = *(const ushort4*)&T[nr][kc];
    *(ushort4*)&dst[dof + (size_t)(n0 + nr) * K_ + k0 + kc] = o;
  }
}

// ---------------- GEMM (m97 structure): C[M,N] = A[M,K] * Bt[N][K], bf16 MFMA ----
// tile 128 x TN, BK=32, 4 waves (2x2).
// OUTMODE 0: f32 store | 2: f32 += | 4: fused QKV(+RoPE) | 5: fused w1/w3 store
template <int TN, int OUTMODE>
__global__ __launch_bounds__(256) void k_gemm2(const bf16_t* __restrict__ A,
                                               const bf16_t* __restrict__ Bt,
                                               float* __restrict__ Cf,
                                               bf16_t* __restrict__ Cb,
                                               bf16_t* __restrict__ aux1,
                                               bf16_t* __restrict__ aux2,
                                               const float* __restrict__ ct,
                                               const float* __restrict__ st,
                                               int M, int N, int K) {
  constexpr int JN = TN / 32;            // B frags per wave
  __shared__ bf16_t As[128 * 32];
  __shared__ bf16_t Bs[TN * 32];
  const int t = threadIdx.x;
  const int w = t >> 6, l = t & 63;
  const int h = l >> 4, r16 = l & 15;
  const int m0 = blockIdx.y * 128, n0 = blockIdx.x * TN;
  const int wr = (w >> 1) * 64;
  const int wc = (w & 1) * (TN / 2);
  const int srow = l >> 2;               // 0..15
  const int skc  = (l & 3) * 8;          // 0,8,16,24

  f32x4 acc[4][JN] = {};

  const bf16_t* pa = &A[(size_t)(m0 + w * 16 + srow) * K + skc];
  const bf16_t* pb = &Bt[(size_t)(n0 + w * 16 + srow) * K + skc];

  for (int k0 = 0; k0 < K; k0 += 32) {
    gll16(pa + k0, &As[(w * 16) * 32]);
    gll16(pa + (size_t)64 * K + k0, &As[(64 + w * 16) * 32]);
    gll16(pb + k0, &Bs[(w * 16) * 32]);
    if constexpr (TN == 128) {
      gll16(pb + (size_t)64 * K + k0, &Bs[(64 + w * 16) * 32]);
    }
    __syncthreads();
    bf16x8 af[4], bfr[JN];
#pragma unroll
    for (int i = 0; i < 4; ++i)
      af[i] = *(const bf16x8*)&As[(wr + i * 16 + r16) * 32 + h * 8];
#pragma unroll
    for (int j = 0; j < JN; ++j)
      bfr[j] = *(const bf16x8*)&Bs[(wc + j * 16 + r16) * 32 + h * 8];
#pragma unroll
    for (int i = 0; i < 4; ++i)
#pragma unroll
      for (int j = 0; j < JN; ++j)
        acc[i][j] = __builtin_amdgcn_mfma_f32_16x16x32_bf16(af[i], bfr[j], acc[i][j], 0, 0, 0);
    __syncthreads();
  }

  if constexpr (OUTMODE == 4) {
    // fused QKV epilogue: region by n0 (0..1023 q, 1024..2047 k, 2048..3071 v)
    const int reg = n0 >> 10;
    const int cbase = (n0 & 1023) + wc;
    if (reg == 2) {
#pragma unroll
      for (int i = 0; i < 4; ++i)
#pragma unroll
        for (int j = 0; j < JN; ++j)
#pragma unroll
          for (int r = 0; r < 4; ++r) {
            int row = m0 + wr + i * 16 + h * 4 + r;
            Cb[(size_t)row * DIM + cbase + j * 16 + r16] = (bf16_t)acc[i][j][r];
          }
    } else {
      bf16_t* dst = reg ? aux2 : aux1;
#pragma unroll
      for (int i = 0; i < 4; ++i)
#pragma unroll
        for (int r = 0; r < 4; ++r) {
          int row = m0 + wr + i * 16 + h * 4 + r;
          float c0 = ct[row * 32 + r16],      s0 = st[row * 32 + r16];
          float c1 = ct[row * 32 + 16 + r16], s1 = st[row * 32 + 16 + r16];
          float lo0 = acc[i][0][r], hi0 = acc[i][2][r];
          float lo1 = acc[i][1][r], hi1 = acc[i][3][r];
          size_t rb = (size_t)row * DIM + cbase;
          dst[rb + r16]      = (bf16_t)(lo0 * c0 - hi0 * s0);
          dst[rb + 32 + r16] = (bf16_t)(hi0 * c0 + lo0 * s0);
          dst[rb + 16 + r16] = (bf16_t)(lo1 * c1 - hi1 * s1);
          dst[rb + 48 + r16] = (bf16_t)(hi1 * c1 + lo1 * s1);
        }
    }
  } else if constexpr (OUTMODE == 5) {
    const int reg = n0 >> 12;              // 0: w1 -> aux1, 1: w3 -> aux2
    bf16_t* dst = reg ? aux2 : aux1;
    const int cbase = (n0 & 4095) + wc;
#pragma unroll
    for (int i = 0; i < 4; ++i)
#pragma unroll
      for (int j = 0; j < JN; ++j)
#pragma unroll
        for (int r = 0; r < 4; ++r) {
          int row = m0 + wr + i * 16 + h * 4 + r;
          dst[(size_t)row * FF + cbase + j * 16 + r16] = (bf16_t)acc[i][j][r];
        }
  } else {
#pragma unroll
    for (int i = 0; i < 4; ++i)
#pragma unroll
      for (int j = 0; j < JN; ++j)
#pragma unroll
        for (int r = 0; r < 4; ++r) {
          int row = m0 + wr + i * 16 + h * 4 + r;
          int col = n0 + wc + j * 16 + r16;
          if (col < N) {
            float vv = acc[i][j][r];
            size_t idx = (size_t)row * N + col;
            if (OUTMODE == 0) Cf[idx] = vv;
            else Cf[idx] += vv;
          }
        }
  }
}

// ------- flash attention: 4 waves/block, swapped-QK layout, causal-paired -------
// Block pq processes q-tile pq then q-tile (31-pq): uniform 33 chunk-units/block,
// 256 blocks = 1/CU, zero tail imbalance.
__global__ __launch_bounds__(256) void k_attn4(const bf16_t* __restrict__ qb,
                                               const bf16_t* __restrict__ kb,
                                               const bf16_t* __restrict__ vb,
                                               bf16_t* __restrict__ ao) {
  __shared__ bf16_t Ks[64][72];       // K chunk: [key][dh]
  __shared__ bf16_t Vt[64][72];       // V chunk transposed: [dh][key]
  __shared__ bf16_t Pl[4][16][72];    // per-wave P: [qrow][key]
  const int pq = blockIdx.x;          // 0..15
  const int head = blockIdx.y;
  const int t = threadIdx.x;
  const int w = t >> 6, l = t & 63;
  const int h = l >> 4, r16 = l & 15;
  const size_t hoff = (size_t)head * HD;
  const int srow = t >> 2;            // 0..63 staging row
  const int ssg  = (t & 3) * 8;       // 0,8,16,24

#pragma unroll
  for (int half = 0; half < 2; ++half) {
    const int qt = half ? (31 - pq) : pq;
    const int q0 = qt * 64 + w * 16;    // this wave's first q row
    const int q_abs = q0 + r16;         // this lane's q row (softmax axis)

    bf16x8 aq[2];
#pragma unroll
    for (int c = 0; c < 2; ++c)
      aq[c] = *(const bf16x8*)&qb[(size_t)(q0 + r16) * DIM + hoff + c * 32 + h * 8];

    f32x4 o[4] = {};
    float mrun = -1e30f, lrun = 0.f;

    const int kend = qt * 64 + 63;
    for (int k0 = 0; k0 <= kend; k0 += 64) {
      // ---- cooperative stage: K direct, V transposed ----
#pragma unroll
      for (int it = 0; it < 2; ++it) {
        bf16x8 kv = *(const bf16x8*)&kb[(size_t)(k0 + srow) * DIM + hoff + ssg + it * 32];
        *(bf16x8*)&Ks[srow][ssg + it * 32] = kv;
      }
#pragma unroll
      for (int it = 0; it < 2; ++it) {
        bf16x8 vv = *(const bf16x8*)&vb[(size_t)(k0 + srow) * DIM + hoff + ssg + it * 32];
#pragma unroll
        for (int j = 0; j < 8; ++j) Vt[ssg + it * 32 + j][srow] = vv[j];
      }
      __syncthreads();

      if (k0 <= q0 + 15) {              // wave-uniform: skip fully-masked chunks
        // ---- scores transposed: D[key][q] ----
        f32x4 sc[4];
        __builtin_amdgcn_s_setprio(1);
#pragma unroll
        for (int tc = 0; tc < 4; ++tc) {
          f32x4 z = {};
          bf16x8 a0 = *(const bf16x8*)&Ks[tc * 16 + r16][h * 8];
          bf16x8 a1 = *(const bf16x8*)&Ks[tc * 16 + r16][32 + h * 8];
          z = __builtin_amdgcn_mfma_f32_16x16x32_bf16(a0, aq[0], z, 0, 0, 0);
          z = __builtin_amdgcn_mfma_f32_16x16x32_bf16(a1, aq[1], z, 0, 0, 0);
          sc[tc] = z;
        }
        __builtin_amdgcn_s_setprio(0);
        // ---- mask + scale; per-lane max over 16 keys ----
        float pmax = -1e30f;
#pragma unroll
        for (int tc = 0; tc < 4; ++tc)
#pragma unroll
          for (int r = 0; r < 4; ++r) {
            int key = k0 + tc * 16 + h * 4 + r;
            float v = sc[tc][r] * 0.125f;
            if (key > q_abs) v = -1e30f;
            sc[tc][r] = v;
            pmax = fmaxf(pmax, v);
          }
        pmax = fmaxf(pmax, __shfl_xor(pmax, 16));
        pmax = fmaxf(pmax, __shfl_xor(pmax, 32));
        float mnew = fmaxf(mrun, pmax);
        float alpha = expf(mrun - mnew);
        mrun = mnew;
        float ssum = 0.f;
#pragma unroll
        for (int tc = 0; tc < 4; ++tc)
#pragma unroll
          for (int r = 0; r < 4; ++r) {
            float pv = expf(sc[tc][r] - mnew);
            sc[tc][r] = pv;
            ssum += pv;
          }
        ssum += __shfl_xor(ssum, 16);
        ssum += __shfl_xor(ssum, 32);
        lrun = lrun * alpha + ssum;
        // ---- write P^T to LDS: Pl[q][key] ----
#pragma unroll
        for (int tc = 0; tc < 4; ++tc)
#pragma unroll
          for (int r = 0; r < 4; ++r)
            Pl[w][r16][tc * 16 + h * 4 + r] = (bf16_t)sc[tc][r];
        // ---- rescale o: alpha for o-row q=h*4+r lives in lane h*4+r ----
        float ar[4];
#pragma unroll
        for (int r = 0; r < 4; ++r) ar[r] = __shfl(alpha, h * 4 + r);
#pragma unroll
        for (int cti = 0; cti < 4; ++cti)
#pragma unroll
          for (int r = 0; r < 4; ++r) o[cti][r] *= ar[r];
        // ---- PV ----
        bf16x8 pa0 = *(const bf16x8*)&Pl[w][r16][h * 8];
        bf16x8 pa1 = *(const bf16x8*)&Pl[w][r16][32 + h * 8];
        __builtin_amdgcn_s_setprio(1);
#pragma unroll
        for (int cti = 0; cti < 4; ++cti) {
          bf16x8 v0 = *(const bf16x8*)&Vt[cti * 16 + r16][h * 8];
          bf16x8 v1 = *(const bf16x8*)&Vt[cti * 16 + r16][32 + h * 8];
          o[cti] = __builtin_amdgcn_mfma_f32_16x16x32_bf16(pa0, v0, o[cti], 0, 0, 0);
          o[cti] = __builtin_amdgcn_mfma_f32_16x16x32_bf16(pa1, v1, o[cti], 0, 0, 0);
        }
        __builtin_amdgcn_s_setprio(0);
      }
      __syncthreads();
    }
    float lr[4];
#pragma unroll
    for (int r = 0; r < 4; ++r) lr[r] = __shfl(lrun, h * 4 + r);
#pragma unroll
    for (int cti = 0; cti < 4; ++cti)
#pragma unroll
      for (int r = 0; r < 4; ++r) {
        int row = q0 + h * 4 + r;
        ao[(size_t)row * DIM + hoff + cti * 16 + r16] = (bf16_t)(o[cti][r] / lr[r]);
      }
  }
}

// ---------------- silu(g1) * g3, bf16 in/out, x8 vectorized ----------------
__global__ __launch_bounds__(256) void k_gate(const bf16_t* __restrict__ g1,
                                              const bf16_t* __restrict__ g3,
                                              bf16_t* __restrict__ out, int n8) {
  int i = blockIdx.x * 256 + threadIdx.x;
  if (i < n8) {
    bf16x8 a = ((const bf16x8*)g1)[i];
    bf16x8 b = ((const bf16x8*)g3)[i];
    bf16x8 o;
#pragma unroll
    for (int j = 0; j < 8; ++j) {
      float f = (float)a[j];
      float s = f / (1.f + expf(-f));
      o[j] = (bf16_t)(s * (float)b[j]);
    }
    ((bf16x8*)out)[i] = o;
  }
}

extern "C" void kernel_launch(void* const* d_in, const int* in_sizes, int n_in,
                              void* d_out, int out_size, void* d_ws, size_t ws_size,
                              hipStream_t stream) {
  const int*   ids  = (const int*)d_in[0];
  const float* temb = (const float*)d_in[1];
  const float* Wq   = (const float*)d_in[2];
  const float* Wk   = (const float*)d_in[3];
  const float* Wv   = (const float*)d_in[4];
  const float* Wo   = (const float*)d_in[5];
  const float* ln1s = (const float*)d_in[6];
  const float* ln1b = (const float*)d_in[7];
  const float* ln2s = (const float*)d_in[8];
  const float* ln2b = (const float*)d_in[9];
  const float* w1   = (const float*)d_in[10];
  const float* w2   = (const float*)d_in[11];
  const float* w3   = (const float*)d_in[12];
  const float* lnfs = (const float*)d_in[13];
  const float* lnfb = (const float*)d_in[14];
  const float* lmh  = (const float*)d_in[15];
  float* out = (float*)d_out;

  char* p = (char*)d_ws;
  size_t used = 0;
  auto alloc = [&](size_t bytes) {
    void* r = (void*)p;
    size_t a = (bytes + 255) & ~(size_t)255;
    p += a; used += a;
    return r;
  };
  // activations + tables
  float*  x     = (float*)alloc((size_t)SEQ * DIM * 4);
  bf16_t* hb    = (bf16_t*)alloc((size_t)SEQ * DIM * 2);
  bf16_t* qb2   = (bf16_t*)alloc((size_t)SEQ * DIM * 2);
  bf16_t* kb2   = (bf16_t*)alloc((size_t)SEQ * DIM * 2);
  bf16_t* vb2   = (bf16_t*)alloc((size_t)SEQ * DIM * 2);
  bf16_t* aob   = (bf16_t*)alloc((size_t)SEQ * DIM * 2);
  bf16_t* g1b   = (bf16_t*)alloc((size_t)SEQ * FF * 2);
  bf16_t* g3b   = (bf16_t*)alloc((size_t)SEQ * FF * 2);
  bf16_t* gateb = (bf16_t*)alloc((size_t)SEQ * FF * 2);
  float*  ctab  = (float*)alloc((size_t)SEQ * 32 * 4);
  float*  stab  = (float*)alloc((size_t)SEQ * 32 * 4);

  const size_t szDD = (size_t)DIM * DIM;    // 1M elems
  const size_t szDF = (size_t)DIM * FF;     // 4M elems
  const size_t wt_bytes = ((size_t)NL * (3 * szDD + szDD + 2 * szDF + szDF) + (size_t)VOCP * DIM) * 2;
  const bool bigws = (ws_size >= used + wt_bytes + (1u << 20));

  bf16_t *bQKV, *bWo, *bW13, *bw2, *blm, *wscratch = nullptr;
  if (bigws) {
    bQKV = (bf16_t*)alloc(NL * 3 * szDD * 2);
    bWo  = (bf16_t*)alloc(NL * szDD * 2);
    bW13 = (bf16_t*)alloc(NL * 2 * szDF * 2);
    bw2  = (bf16_t*)alloc(NL * szDF * 2);
    blm  = (bf16_t*)alloc((size_t)VOCP * DIM * 2);
  } else {
    wscratch = (bf16_t*)alloc(2 * szDF * 2);   // enough for fused w13 of one layer
    bQKV = bWo = bW13 = bw2 = blm = wscratch;
  }

  auto cvt = [&](const float* src, bf16_t* dst, int K_, int N_, int Npad_, int nz, size_t dstride) {
    dim3 g(Npad_ / 64, K_ / 64, nz);
    k_cvt_t<<<g, 256, 0, stream>>>(src, dst, K_, N_, Npad_, dstride);
  };

  if (bigws) {
    cvt(Wq, bQKV,             DIM, DIM, DIM, NL, 3 * szDD);
    cvt(Wk, bQKV + szDD,      DIM, DIM, DIM, NL, 3 * szDD);
    cvt(Wv, bQKV + 2 * szDD,  DIM, DIM, DIM, NL, 3 * szDD);
    cvt(Wo, bWo,              DIM, DIM, DIM, NL, szDD);
    cvt(w1, bW13,             DIM, FF,  FF,  NL, 2 * szDF);
    cvt(w3, bW13 + szDF,      DIM, FF,  FF,  NL, 2 * szDF);
    cvt(w2, bw2,              FF,  DIM, DIM, NL, szDF);
    cvt(lmh, blm,             DIM, VOC, VOCP, 1, 0);
  }
  auto wpQKV = [&](int lyr) -> bf16_t* {
    if (bigws) return bQKV + (size_t)lyr * 3 * szDD;
    cvt(Wq + (size_t)lyr * szDD, wscratch,            DIM, DIM, DIM, 1, 0);
    cvt(Wk + (size_t)lyr * szDD, wscratch + szDD,     DIM, DIM, DIM, 1, 0);
    cvt(Wv + (size_t)lyr * szDD, wscratch + 2 * szDD, DIM, DIM, DIM, 1, 0);
    return wscratch;
  };
  auto wpW13 = [&](int lyr) -> bf16_t* {
    if (bigws) return bW13 + (size_t)lyr * 2 * szDF;
    cvt(w1 + (size_t)lyr * szDF, wscratch,        DIM, FF, FF, 1, 0);
    cvt(w3 + (size_t)lyr * szDF, wscratch + szDF, DIM, FF, FF, 1, 0);
    return wscratch;
  };
  auto wp1 = [&](bf16_t* big, const float* src, int lyr, int K_, int N_, int Npad_) -> bf16_t* {
    if (bigws) return big + (size_t)lyr * Npad_ * K_;
    cvt(src + (size_t)lyr * K_ * N_, wscratch, K_, N_, Npad_, 1, 0);
    return wscratch;
  };

  k_rtab<<<(SEQ * 32) / 256, 256, 0, stream>>>(ctab, stab);
  k_embed<<<SEQ, 256, 0, stream>>>(ids, temb, x);

  dim3 gQKV(3 * DIM / 128, SEQ / 128);   // 24 x 16 = 384
  dim3 gDD(DIM / 64, SEQ / 128);         // 16 x 16 = 256
  dim3 gW13(2 * FF / 128, SEQ / 128);    // 64 x 16 = 1024
  dim3 gLM(VOCP / 64, SEQ / 128);        // 22 x 16 = 352
  dim3 gAt(SEQ / 128, NH);               // 16 pairs x 16 heads = 256

  for (int l = 0; l < NL; ++l) {
    k_ln<<<SEQ / 4, 256, 0, stream>>>(x, ln1s + (size_t)l * DIM, ln1b + (size_t)l * DIM, hb);
    k_gemm2<128, 4><<<gQKV, 256, 0, stream>>>(hb, wpQKV(l), nullptr, vb2, qb2, kb2,
                                              ctab, stab, SEQ, 3 * DIM, DIM);
    k_attn4<<<gAt, 256, 0, stream>>>(qb2, kb2, vb2, aob);
    k_gemm2<64, 2><<<gDD, 256, 0, stream>>>(aob, wp1(bWo, Wo, l, DIM, DIM, DIM), x, nullptr,
                                            nullptr, nullptr, nullptr, nullptr, SEQ, DIM, DIM);
    k_ln<<<SEQ / 4, 256, 0, stream>>>(x, ln2s + (size_t)l * DIM, ln2b + (size_t)l * DIM, hb);
    k_gemm2<128, 5><<<gW13, 256, 0, stream>>>(hb, wpW13(l), nullptr, nullptr, g1b, g3b,
                                              nullptr, nullptr, SEQ, 2 * FF, DIM);
    k_gate<<<(SEQ * FF / 8 + 255) / 256, 256, 0, stream>>>(g1b, g3b, gateb, SEQ * FF / 8);
    k_gemm2<64, 2><<<gDD, 256, 0, stream>>>(gateb, wp1(bw2, w2, l, FF, DIM, DIM), x, nullptr,
                                            nullptr, nullptr, nullptr, nullptr, SEQ, DIM, FF);
  }
  k_ln<<<SEQ / 4, 256, 0, stream>>>(x, lnfs, lnfb, hb);
  k_gemm2<64, 0><<<gLM, 256, 0, stream>>>(hb, bigws ? blm : wp1(blm, lmh, 0, DIM, VOC, VOCP),
                                          out, nullptr, nullptr, nullptr, nullptr, nullptr,
                                          SEQ, VOC, DIM);
}

// Round 8
// 3618.050 us; speedup vs baseline: 4.1918x; 1.0285x over previous
//
#include <hip/hip_runtime.h>
#include <math.h>

// ---- problem constants ----
constexpr int SEQ = 2048;
constexpr int DIM = 1024;
constexpr int NH  = 16;
constexpr int HD  = 64;
constexpr int FF  = 4096;
constexpr int NL  = 12;
constexpr int VOC = 1400;
constexpr int VOCP = 1408;   // padded to 64

typedef __bf16 bf16_t;
typedef __bf16 bf16x8 __attribute__((ext_vector_type(8)));
typedef float  f32x4  __attribute__((ext_vector_type(4)));

typedef __attribute__((address_space(1))) const void GV;
typedef __attribute__((address_space(3))) void LV;

__device__ __forceinline__ void gll16(const bf16_t* g, bf16_t* l) {
  __builtin_amdgcn_global_load_lds((GV*)g, (LV*)l, 16, 0, 0);
}

// ---------------- embedding gather ----------------
__global__ __launch_bounds__(256) void k_embed(const int* __restrict__ ids,
                                               const float* __restrict__ emb,
                                               float* __restrict__ x) {
  int s = blockIdx.x;
  int d = threadIdx.x * 4;
  const float4 v = *(const float4*)&emb[(size_t)ids[s] * DIM + d];
  *(float4*)&x[(size_t)s * DIM + d] = v;
}

// ---------------- RoPE cos/sin table: [s][i], i = freq idx 0..31 ----------------
__global__ __launch_bounds__(256) void k_rtab(float* __restrict__ ct,
                                              float* __restrict__ st) {
  int id = blockIdx.x * 256 + threadIdx.x;   // SEQ*32
  int i = id & 31;
  int s = id >> 5;
  float ang = (float)s * powf(10000.f, -(float)i * (1.f / 32.f));
  float sn, cs;
  sincosf(ang, &sn, &cs);
  ct[id] = cs;
  st[id] = sn;
}

// ------- layernorm (f32 in -> bf16 out), 4 rows/block, 1 wave per row -------
__global__ __launch_bounds__(256) void k_ln(const float* __restrict__ x,
                                            const float* __restrict__ sc,
                                            const float* __restrict__ bi,
                                            bf16_t* __restrict__ out) {
  int s = blockIdx.x * 4 + (threadIdx.x >> 6);
  int l = threadIdx.x & 63;
  const float* xr = x + (size_t)s * DIM;
  float4 v[4];
  float sum = 0.f, sq = 0.f;
#pragma unroll
  for (int i = 0; i < 4; ++i) {
    v[i] = *(const float4*)&xr[i * 256 + l * 4];
#pragma unroll
    for (int j = 0; j < 4; ++j) { sum += v[i][j]; sq += v[i][j] * v[i][j]; }
  }
#pragma unroll
  for (int d = 1; d < 64; d <<= 1) {
    sum += __shfl_xor(sum, d);
    sq  += __shfl_xor(sq, d);
  }
  float mean = sum * (1.f / DIM);
  float var  = sq * (1.f / DIM) - mean * mean;
  float inv  = rsqrtf(var + 1e-5f);
#pragma unroll
  for (int i = 0; i < 4; ++i) {
    int off = i * 256 + l * 4;
    float4 scv = *(const float4*)&sc[off];
    float4 biv = *(const float4*)&bi[off];
#pragma unroll
    for (int j = 0; j < 4; ++j) {
      float o = (v[i][j] - mean) * inv * scv[j] + biv[j];
      out[(size_t)s * DIM + off + j] = (bf16_t)o;
    }
  }
}

// ------- weight convert + transpose: src[K][N] f32 -> dst[...][K] bf16 -------
// blockIdx.z = matrix idx; dst layer stride = dstride elems. Zero-fills n >= N.
// imode 0: dst row = n (plain B^T).
// imode 1: w1-interleave: feature f -> row (f>>4)*32 + (f&15)
// imode 2: w3-interleave: feature f -> row (f>>4)*32 + 16 + (f&15)
__global__ __launch_bounds__(256) void k_cvt_t(const float* __restrict__ src,
                                               bf16_t* __restrict__ dst,
                                               int K_, int N_, int Npad_,
                                               size_t dstride, int imode) {
  __shared__ bf16_t T[64][66];
  const int k0 = blockIdx.y * 64;
  const int n0 = blockIdx.x * 64;
  const size_t so = (size_t)blockIdx.z * K_ * N_;
  const size_t dof = (size_t)blockIdx.z * dstride;
  const int t = threadIdx.x;
  const int kk = t >> 4;
  const int nn = (t & 15) * 4;
#pragma unroll
  for (int it = 0; it < 4; ++it) {
    int krow = kk + it * 16;
    float4 v = {0.f, 0.f, 0.f, 0.f};
    if (n0 + nn < N_) v = *(const float4*)&src[so + (size_t)(k0 + krow) * N_ + n0 + nn];
#pragma unroll
    for (int q = 0; q < 4; ++q) T[nn + q][krow] = (bf16_t)v[q];
  }
  __syncthreads();
#pragma unroll
  for (int it = 0; it < 4; ++it) {
    int c = it * 256 + t;
    int nr = c >> 4;
    int kc = (c & 15) * 4;
    int f = n0 + nr;
    int drow = (imode == 0) ? f : ((f >> 4) * 32 + ((imode == 2) ? 16 : 0) + (f & 15));
    ushort4 o = *(const ushort4*)&T[nr][kc];
    *(ushort4*)&dst[dof + (size_t)drow * K_ + k0 + kc] = o;
  }
}

// ---------------- GEMM (m97 structure): C[M,N] = A[M,K] * Bt[N][K], bf16 MFMA ----
// tile 128 x TN, BK=32, 4 waves (2x2).
// OUTMODE 0: f32 store | 2: f32 += | 4: fused QKV(+RoPE) | 6: interleaved silu-gate
template <int TN, int OUTMODE>
__global__ __launch_bounds__(256) void k_gemm2(const bf16_t* __restrict__ A,
                                               const bf16_t* __restrict__ Bt,
                                               float* __restrict__ Cf,
                                               bf16_t* __restrict__ Cb,
                                               bf16_t* __restrict__ aux1,
                                               bf16_t* __restrict__ aux2,
                                               const float* __restrict__ ct,
                                               const float* __restrict__ st,
                                               int M, int N, int K) {
  constexpr int JN = TN / 32;            // B frags per wave
  __shared__ bf16_t As[128 * 32];
  __shared__ bf16_t Bs[TN * 32];
  const int t = threadIdx.x;
  const int w = t >> 6, l = t & 63;
  const int h = l >> 4, r16 = l & 15;
  const int m0 = blockIdx.y * 128, n0 = blockIdx.x * TN;
  const int wr = (w >> 1) * 64;
  const int wc = (w & 1) * (TN / 2);
  const int srow = l >> 2;               // 0..15
  const int skc  = (l & 3) * 8;          // 0,8,16,24

  f32x4 acc[4][JN] = {};

  const bf16_t* pa = &A[(size_t)(m0 + w * 16 + srow) * K + skc];
  const bf16_t* pb = &Bt[(size_t)(n0 + w * 16 + srow) * K + skc];

  for (int k0 = 0; k0 < K; k0 += 32) {
    gll16(pa + k0, &As[(w * 16) * 32]);
    gll16(pa + (size_t)64 * K + k0, &As[(64 + w * 16) * 32]);
    gll16(pb + k0, &Bs[(w * 16) * 32]);
    if constexpr (TN == 128) {
      gll16(pb + (size_t)64 * K + k0, &Bs[(64 + w * 16) * 32]);
    }
    __syncthreads();
    bf16x8 af[4], bfr[JN];
#pragma unroll
    for (int i = 0; i < 4; ++i)
      af[i] = *(const bf16x8*)&As[(wr + i * 16 + r16) * 32 + h * 8];
#pragma unroll
    for (int j = 0; j < JN; ++j)
      bfr[j] = *(const bf16x8*)&Bs[(wc + j * 16 + r16) * 32 + h * 8];
#pragma unroll
    for (int i = 0; i < 4; ++i)
#pragma unroll
      for (int j = 0; j < JN; ++j)
        acc[i][j] = __builtin_amdgcn_mfma_f32_16x16x32_bf16(af[i], bfr[j], acc[i][j], 0, 0, 0);
    __syncthreads();
  }

  if constexpr (OUTMODE == 4) {
    // fused QKV epilogue: region by n0 (0..1023 q, 1024..2047 k, 2048..3071 v)
    const int reg = n0 >> 10;
    const int cbase = (n0 & 1023) + wc;
    if (reg == 2) {
#pragma unroll
      for (int i = 0; i < 4; ++i)
#pragma unroll
        for (int j = 0; j < JN; ++j)
#pragma unroll
          for (int r = 0; r < 4; ++r) {
            int row = m0 + wr + i * 16 + h * 4 + r;
            Cb[(size_t)row * DIM + cbase + j * 16 + r16] = (bf16_t)acc[i][j][r];
          }
    } else {
      bf16_t* dst = reg ? aux2 : aux1;
#pragma unroll
      for (int i = 0; i < 4; ++i)
#pragma unroll
        for (int r = 0; r < 4; ++r) {
          int row = m0 + wr + i * 16 + h * 4 + r;
          float c0 = ct[row * 32 + r16],      s0 = st[row * 32 + r16];
          float c1 = ct[row * 32 + 16 + r16], s1 = st[row * 32 + 16 + r16];
          float lo0 = acc[i][0][r], hi0 = acc[i][2][r];
          float lo1 = acc[i][1][r], hi1 = acc[i][3][r];
          size_t rb = (size_t)row * DIM + cbase;
          dst[rb + r16]      = (bf16_t)(lo0 * c0 - hi0 * s0);
          dst[rb + 32 + r16] = (bf16_t)(hi0 * c0 + lo0 * s0);
          dst[rb + 16 + r16] = (bf16_t)(lo1 * c1 - hi1 * s1);
          dst[rb + 48 + r16] = (bf16_t)(hi1 * c1 + lo1 * s1);
        }
    }
  } else if constexpr (OUTMODE == 6) {
    // interleaved w1/w3 -> fused silu-gate. j even = w1, j odd = w3 (same features).
    // feature f = fbase + (j>>1)*16 + r16, fbase = ((n0+wc)>>5)*16
    const int fbase = ((n0 + wc) >> 5) * 16;
#pragma unroll
    for (int i = 0; i < 4; ++i)
#pragma unroll
      for (int r = 0; r < 4; ++r) {
        int row = m0 + wr + i * 16 + h * 4 + r;
        float a0 = acc[i][0][r], b0 = acc[i][1][r];
        float a1 = acc[i][2][r], b1 = acc[i][3][r];
        float g0 = a0 / (1.f + expf(-a0)) * b0;
        float g1v = a1 / (1.f + expf(-a1)) * b1;
        size_t rb = (size_t)row * FF + fbase;
        aux1[rb + r16]      = (bf16_t)g0;
        aux1[rb + 16 + r16] = (bf16_t)g1v;
      }
  } else {
#pragma unroll
    for (int i = 0; i < 4; ++i)
#pragma unroll
      for (int j = 0; j < JN; ++j)
#pragma unroll
        for (int r = 0; r < 4; ++r) {
          int row = m0 + wr + i * 16 + h * 4 + r;
          int col = n0 + wc + j * 16 + r16;
          if (col < N) {
            float vv = acc[i][j][r];
            size_t idx = (size_t)row * N + col;
            if (OUTMODE == 0) Cf[idx] = vv;
            else Cf[idx] += vv;
          }
        }
  }
}

// ------- flash attention: 4 waves/block, swapped-QK layout, causal-paired -------
__global__ __launch_bounds__(256) void k_attn4(const bf16_t* __restrict__ qb,
                                               const bf16_t* __restrict__ kb,
                                               const bf16_t* __restrict__ vb,
                                               bf16_t* __restrict__ ao) {
  __shared__ bf16_t Ks[64][72];       // K chunk: [key][dh]
  __shared__ bf16_t Vt[64][72];       // V chunk transposed: [dh][key]
  __shared__ bf16_t Pl[4][16][72];    // per-wave P: [qrow][key]
  const int pq = blockIdx.x;          // 0..15
  const int head = blockIdx.y;
  const int t = threadIdx.x;
  const int w = t >> 6, l = t & 63;
  const int h = l >> 4, r16 = l & 15;
  const size_t hoff = (size_t)head * HD;
  const int srow = t >> 2;            // 0..63 staging row
  const int ssg  = (t & 3) * 8;       // 0,8,16,24

#pragma unroll
  for (int half = 0; half < 2; ++half) {
    const int qt = half ? (31 - pq) : pq;
    const int q0 = qt * 64 + w * 16;    // this wave's first q row
    const int q_abs = q0 + r16;         // this lane's q row (softmax axis)

    bf16x8 aq[2];
#pragma unroll
    for (int c = 0; c < 2; ++c)
      aq[c] = *(const bf16x8*)&qb[(size_t)(q0 + r16) * DIM + hoff + c * 32 + h * 8];

    f32x4 o[4] = {};
    float mrun = -1e30f, lrun = 0.f;

    const int kend = qt * 64 + 63;
    for (int k0 = 0; k0 <= kend; k0 += 64) {
      // ---- cooperative stage: K direct, V transposed ----
#pragma unroll
      for (int it = 0; it < 2; ++it) {
        bf16x8 kv = *(const bf16x8*)&kb[(size_t)(k0 + srow) * DIM + hoff + ssg + it * 32];
        *(bf16x8*)&Ks[srow][ssg + it * 32] = kv;
      }
#pragma unroll
      for (int it = 0; it < 2; ++it) {
        bf16x8 vv = *(const bf16x8*)&vb[(size_t)(k0 + srow) * DIM + hoff + ssg + it * 32];
#pragma unroll
        for (int j = 0; j < 8; ++j) Vt[ssg + it * 32 + j][srow] = vv[j];
      }
      __syncthreads();

      if (k0 <= q0 + 15) {              // wave-uniform: skip fully-masked chunks
        // ---- scores transposed: D[key][q] ----
        f32x4 sc[4];
        __builtin_amdgcn_s_setprio(1);
#pragma unroll
        for (int tc = 0; tc < 4; ++tc) {
          f32x4 z = {};
          bf16x8 a0 = *(const bf16x8*)&Ks[tc * 16 + r16][h * 8];
          bf16x8 a1 = *(const bf16x8*)&Ks[tc * 16 + r16][32 + h * 8];
          z = __builtin_amdgcn_mfma_f32_16x16x32_bf16(a0, aq[0], z, 0, 0, 0);
          z = __builtin_amdgcn_mfma_f32_16x16x32_bf16(a1, aq[1], z, 0, 0, 0);
          sc[tc] = z;
        }
        __builtin_amdgcn_s_setprio(0);
        // ---- mask + scale; per-lane max over 16 keys ----
        float pmax = -1e30f;
#pragma unroll
        for (int tc = 0; tc < 4; ++tc)
#pragma unroll
          for (int r = 0; r < 4; ++r) {
            int key = k0 + tc * 16 + h * 4 + r;
            float v = sc[tc][r] * 0.125f;
            if (key > q_abs) v = -1e30f;
            sc[tc][r] = v;
            pmax = fmaxf(pmax, v);
          }
        pmax = fmaxf(pmax, __shfl_xor(pmax, 16));
        pmax = fmaxf(pmax, __shfl_xor(pmax, 32));
        float mnew = fmaxf(mrun, pmax);
        float alpha = expf(mrun - mnew);
        mrun = mnew;
        float ssum = 0.f;
#pragma unroll
        for (int tc = 0; tc < 4; ++tc)
#pragma unroll
          for (int r = 0; r < 4; ++r) {
            float pv = expf(sc[tc][r] - mnew);
            sc[tc][r] = pv;
            ssum += pv;
          }
        ssum += __shfl_xor(ssum, 16);
        ssum += __shfl_xor(ssum, 32);
        lrun = lrun * alpha + ssum;
        // ---- write P^T to LDS: Pl[q][key] ----
#pragma unroll
        for (int tc = 0; tc < 4; ++tc)
#pragma unroll
          for (int r = 0; r < 4; ++r)
            Pl[w][r16][tc * 16 + h * 4 + r] = (bf16_t)sc[tc][r];
        // ---- rescale o: alpha for o-row q=h*4+r lives in lane h*4+r ----
        float ar[4];
#pragma unroll
        for (int r = 0; r < 4; ++r) ar[r] = __shfl(alpha, h * 4 + r);
#pragma unroll
        for (int cti = 0; cti < 4; ++cti)
#pragma unroll
          for (int r = 0; r < 4; ++r) o[cti][r] *= ar[r];
        // ---- PV ----
        bf16x8 pa0 = *(const bf16x8*)&Pl[w][r16][h * 8];
        bf16x8 pa1 = *(const bf16x8*)&Pl[w][r16][32 + h * 8];
        __builtin_amdgcn_s_setprio(1);
#pragma unroll
        for (int cti = 0; cti < 4; ++cti) {
          bf16x8 v0 = *(const bf16x8*)&Vt[cti * 16 + r16][h * 8];
          bf16x8 v1 = *(const bf16x8*)&Vt[cti * 16 + r16][32 + h * 8];
          o[cti] = __builtin_amdgcn_mfma_f32_16x16x32_bf16(pa0, v0, o[cti], 0, 0, 0);
          o[cti] = __builtin_amdgcn_mfma_f32_16x16x32_bf16(pa1, v1, o[cti], 0, 0, 0);
        }
        __builtin_amdgcn_s_setprio(0);
      }
      __syncthreads();
    }
    float lr[4];
#pragma unroll
    for (int r = 0; r < 4; ++r) lr[r] = __shfl(lrun, h * 4 + r);
#pragma unroll
    for (int cti = 0; cti < 4; ++cti)
#pragma unroll
      for (int r = 0; r < 4; ++r) {
        int row = q0 + h * 4 + r;
        ao[(size_t)row * DIM + hoff + cti * 16 + r16] = (bf16_t)(o[cti][r] / lr[r]);
      }
  }
}

extern "C" void kernel_launch(void* const* d_in, const int* in_sizes, int n_in,
                              void* d_out, int out_size, void* d_ws, size_t ws_size,
                              hipStream_t stream) {
  const int*   ids  = (const int*)d_in[0];
  const float* temb = (const float*)d_in[1];
  const float* Wq   = (const float*)d_in[2];
  const float* Wk   = (const float*)d_in[3];
  const float* Wv   = (const float*)d_in[4];
  const float* Wo   = (const float*)d_in[5];
  const float* ln1s = (const float*)d_in[6];
  const float* ln1b = (const float*)d_in[7];
  const float* ln2s = (const float*)d_in[8];
  const float* ln2b = (const float*)d_in[9];
  const float* w1   = (const float*)d_in[10];
  const float* w2   = (const float*)d_in[11];
  const float* w3   = (const float*)d_in[12];
  const float* lnfs = (const float*)d_in[13];
  const float* lnfb = (const float*)d_in[14];
  const float* lmh  = (const float*)d_in[15];
  float* out = (float*)d_out;

  char* p = (char*)d_ws;
  size_t used = 0;
  auto alloc = [&](size_t bytes) {
    void* r = (void*)p;
    size_t a = (bytes + 255) & ~(size_t)255;
    p += a; used += a;
    return r;
  };
  // activations + tables
  float*  x     = (float*)alloc((size_t)SEQ * DIM * 4);
  bf16_t* hb    = (bf16_t*)alloc((size_t)SEQ * DIM * 2);
  bf16_t* qb2   = (bf16_t*)alloc((size_t)SEQ * DIM * 2);
  bf16_t* kb2   = (bf16_t*)alloc((size_t)SEQ * DIM * 2);
  bf16_t* vb2   = (bf16_t*)alloc((size_t)SEQ * DIM * 2);
  bf16_t* aob   = (bf16_t*)alloc((size_t)SEQ * DIM * 2);
  bf16_t* gateb = (bf16_t*)alloc((size_t)SEQ * FF * 2);
  float*  ctab  = (float*)alloc((size_t)SEQ * 32 * 4);
  float*  stab  = (float*)alloc((size_t)SEQ * 32 * 4);

  const size_t szDD = (size_t)DIM * DIM;    // 1M elems
  const size_t szDF = (size_t)DIM * FF;     // 4M elems
  const size_t wt_bytes = ((size_t)NL * (3 * szDD + szDD + 2 * szDF + szDF) + (size_t)VOCP * DIM) * 2;
  const bool bigws = (ws_size >= used + wt_bytes + (1u << 20));

  bf16_t *bQKV, *bWo, *bW13, *bw2, *blm, *wscratch = nullptr;
  if (bigws) {
    bQKV = (bf16_t*)alloc(NL * 3 * szDD * 2);
    bWo  = (bf16_t*)alloc(NL * szDD * 2);
    bW13 = (bf16_t*)alloc(NL * 2 * szDF * 2);
    bw2  = (bf16_t*)alloc(NL * szDF * 2);
    blm  = (bf16_t*)alloc((size_t)VOCP * DIM * 2);
  } else {
    wscratch = (bf16_t*)alloc(2 * szDF * 2);   // enough for fused w13 of one layer
    bQKV = bWo = bW13 = bw2 = blm = wscratch;
  }

  auto cvt = [&](const float* src, bf16_t* dst, int K_, int N_, int Npad_, int nz,
                 size_t dstride, int imode) {
    dim3 g(Npad_ / 64, K_ / 64, nz);
    k_cvt_t<<<g, 256, 0, stream>>>(src, dst, K_, N_, Npad_, dstride, imode);
  };

  if (bigws) {
    cvt(Wq, bQKV,             DIM, DIM, DIM, NL, 3 * szDD, 0);
    cvt(Wk, bQKV + szDD,      DIM, DIM, DIM, NL, 3 * szDD, 0);
    cvt(Wv, bQKV + 2 * szDD,  DIM, DIM, DIM, NL, 3 * szDD, 0);
    cvt(Wo, bWo,              DIM, DIM, DIM, NL, szDD, 0);
    cvt(w1, bW13,             DIM, FF,  FF,  NL, 2 * szDF, 1);   // interleaved even
    cvt(w3, bW13,             DIM, FF,  FF,  NL, 2 * szDF, 2);   // interleaved odd
    cvt(w2, bw2,              FF,  DIM, DIM, NL, szDF, 0);
    cvt(lmh, blm,             DIM, VOC, VOCP, 1, 0, 0);
  }
  auto wpQKV = [&](int lyr) -> bf16_t* {
    if (bigws) return bQKV + (size_t)lyr * 3 * szDD;
    cvt(Wq + (size_t)lyr * szDD, wscratch,            DIM, DIM, DIM, 1, 0, 0);
    cvt(Wk + (size_t)lyr * szDD, wscratch + szDD,     DIM, DIM, DIM, 1, 0, 0);
    cvt(Wv + (size_t)lyr * szDD, wscratch + 2 * szDD, DIM, DIM, DIM, 1, 0, 0);
    return wscratch;
  };
  auto wpW13 = [&](int lyr) -> bf16_t* {
    if (bigws) return bW13 + (size_t)lyr * 2 * szDF;
    cvt(w1 + (size_t)lyr * szDF, wscratch, DIM, FF, FF, 1, 0, 1);
    cvt(w3 + (size_t)lyr * szDF, wscratch, DIM, FF, FF, 1, 0, 2);
    return wscratch;
  };
  auto wp1 = [&](bf16_t* big, const float* src, int lyr, int K_, int N_, int Npad_) -> bf16_t* {
    if (bigws) return big + (size_t)lyr * Npad_ * K_;
    cvt(src + (size_t)lyr * K_ * N_, wscratch, K_, N_, Npad_, 1, 0, 0);
    return wscratch;
  };

  k_rtab<<<(SEQ * 32) / 256, 256, 0, stream>>>(ctab, stab);
  k_embed<<<SEQ, 256, 0, stream>>>(ids, temb, x);

  dim3 gQKV(3 * DIM / 128, SEQ / 128);   // 24 x 16 = 384
  dim3 gDD(DIM / 64, SEQ / 128);         // 16 x 16 = 256
  dim3 gW13(2 * FF / 128, SEQ / 128);    // 64 x 16 = 1024
  dim3 gLM(VOCP / 64, SEQ / 128);        // 22 x 16 = 352
  dim3 gAt(SEQ / 128, NH);               // 16 pairs x 16 heads = 256

  for (int l = 0; l < NL; ++l) {
    k_ln<<<SEQ / 4, 256, 0, stream>>>(x, ln1s + (size_t)l * DIM, ln1b + (size_t)l * DIM, hb);
    k_gemm2<128, 4><<<gQKV, 256, 0, stream>>>(hb, wpQKV(l), nullptr, vb2, qb2, kb2,
                                              ctab, stab, SEQ, 3 * DIM, DIM);
    k_attn4<<<gAt, 256, 0, stream>>>(qb2, kb2, vb2, aob);
    k_gemm2<64, 2><<<gDD, 256, 0, stream>>>(aob, wp1(bWo, Wo, l, DIM, DIM, DIM), x, nullptr,
                                            nullptr, nullptr, nullptr, nullptr, SEQ, DIM, DIM);
    k_ln<<<SEQ / 4, 256, 0, stream>>>(x, ln2s + (size_t)l * DIM, ln2b + (size_t)l * DIM, hb);
    k_gemm2<128, 6><<<gW13, 256, 0, stream>>>(hb, wpW13(l), nullptr, nullptr, gateb, nullptr,
                                              nullptr, nullptr, SEQ, 2 * FF, DIM);
    k_gemm2<64, 2><<<gDD, 256, 0, stream>>>(gateb, wp1(bw2, w2, l, FF, DIM, DIM), x, nullptr,
                                            nullptr, nullptr, nullptr, nullptr, SEQ, DIM, FF);
  }
  k_ln<<<SEQ / 4, 256, 0, stream>>>(x, lnfs, lnfb, hb);
  k_gemm2<64, 0><<<gLM, 256, 0, stream>>>(hb, bigws ? blm : wp1(blm, lmh, 0, DIM, VOC, VOCP),
                                          out, nullptr, nullptr, nullptr, nullptr, nullptr,
                                          SEQ, VOC, DIM);
}

// Round 9
// 3296.176 us; speedup vs baseline: 4.6011x; 1.0977x over previous
//
#include <hip/hip_runtime.h>
#include <math.h>

// ---- problem constants ----
constexpr int SEQ = 2048;
constexpr int DIM = 1024;
constexpr int NH  = 16;
constexpr int HD  = 64;
constexpr int FF  = 4096;
constexpr int NL  = 12;
constexpr int VOC = 1400;
constexpr int VOCP = 1408;   // padded to 64

typedef __bf16 bf16_t;
typedef __bf16 bf16x8 __attribute__((ext_vector_type(8)));
typedef float  f32x4  __attribute__((ext_vector_type(4)));

typedef __attribute__((address_space(1))) const void GV;
typedef __attribute__((address_space(3))) void LV;

__device__ __forceinline__ void gll16(const bf16_t* g, bf16_t* l) {
  __builtin_amdgcn_global_load_lds((GV*)g, (LV*)l, 16, 0, 0);
}

// ---------------- embedding gather ----------------
__global__ __launch_bounds__(256) void k_embed(const int* __restrict__ ids,
                                               const float* __restrict__ emb,
                                               float* __restrict__ x) {
  int s = blockIdx.x;
  int d = threadIdx.x * 4;
  const float4 v = *(const float4*)&emb[(size_t)ids[s] * DIM + d];
  *(float4*)&x[(size_t)s * DIM + d] = v;
}

// ---------------- RoPE cos/sin table: [s][i], i = freq idx 0..31 ----------------
__global__ __launch_bounds__(256) void k_rtab(float* __restrict__ ct,
                                              float* __restrict__ st) {
  int id = blockIdx.x * 256 + threadIdx.x;   // SEQ*32
  int i = id & 31;
  int s = id >> 5;
  float ang = (float)s * powf(10000.f, -(float)i * (1.f / 32.f));
  float sn, cs;
  sincosf(ang, &sn, &cs);
  ct[id] = cs;
  st[id] = sn;
}

// ------- layernorm (f32 in -> bf16 out), 4 rows/block, 1 wave per row -------
__global__ __launch_bounds__(256) void k_ln(const float* __restrict__ x,
                                            const float* __restrict__ sc,
                                            const float* __restrict__ bi,
                                            bf16_t* __restrict__ out) {
  int s = blockIdx.x * 4 + (threadIdx.x >> 6);
  int l = threadIdx.x & 63;
  const float* xr = x + (size_t)s * DIM;
  float4 v[4];
  float sum = 0.f, sq = 0.f;
#pragma unroll
  for (int i = 0; i < 4; ++i) {
    v[i] = *(const float4*)&xr[i * 256 + l * 4];
#pragma unroll
    for (int j = 0; j < 4; ++j) { sum += v[i][j]; sq += v[i][j] * v[i][j]; }
  }
#pragma unroll
  for (int d = 1; d < 64; d <<= 1) {
    sum += __shfl_xor(sum, d);
    sq  += __shfl_xor(sq, d);
  }
  float mean = sum * (1.f / DIM);
  float var  = sq * (1.f / DIM) - mean * mean;
  float inv  = rsqrtf(var + 1e-5f);
#pragma unroll
  for (int i = 0; i < 4; ++i) {
    int off = i * 256 + l * 4;
    float4 scv = *(const float4*)&sc[off];
    float4 biv = *(const float4*)&bi[off];
#pragma unroll
    for (int j = 0; j < 4; ++j) {
      float o = (v[i][j] - mean) * inv * scv[j] + biv[j];
      out[(size_t)s * DIM + off + j] = (bf16_t)o;
    }
  }
}

// ------- weight convert + transpose: src[K][N] f32 -> dst[...][K] bf16 -------
// imode 0: dst row = n. imode 1: w1 f -> (f>>4)*32+(f&15). imode 2: w3 -> +16.
__global__ __launch_bounds__(256) void k_cvt_t(const float* __restrict__ src,
                                               bf16_t* __restrict__ dst,
                                               int K_, int N_, int Npad_,
                                               size_t dstride, int imode) {
  __shared__ bf16_t T[64][66];
  const int k0 = blockIdx.y * 64;
  const int n0 = blockIdx.x * 64;
  const size_t so = (size_t)blockIdx.z * K_ * N_;
  const size_t dof = (size_t)blockIdx.z * dstride;
  const int t = threadIdx.x;
  const int kk = t >> 4;
  const int nn = (t & 15) * 4;
#pragma unroll
  for (int it = 0; it < 4; ++it) {
    int krow = kk + it * 16;
    float4 v = {0.f, 0.f, 0.f, 0.f};
    if (n0 + nn < N_) v = *(const float4*)&src[so + (size_t)(k0 + krow) * N_ + n0 + nn];
#pragma unroll
    for (int q = 0; q < 4; ++q) T[nn + q][krow] = (bf16_t)v[q];
  }
  __syncthreads();
#pragma unroll
  for (int it = 0; it < 4; ++it) {
    int c = it * 256 + t;
    int nr = c >> 4;
    int kc = (c & 15) * 4;
    int f = n0 + nr;
    int drow = (imode == 0) ? f : ((f >> 4) * 32 + ((imode == 2) ? 16 : 0) + (f & 15));
    ushort4 o = *(const ushort4*)&T[nr][kc];
    *(ushort4*)&dst[dof + (size_t)drow * K_ + k0 + kc] = o;
  }
}

// ---------------- GEMM: C[M,N] = A[M,K] * Bt[N][K], bf16 MFMA ----------------
// tile 128 x TN, BK=64, 4 waves (2x2). XOR-swizzled staging: global chunk
// kappa^(row&7) lands at LDS chunk kappa; reader at p=(kk*4+h)^(r16&7)
// recovers the true chunk -> conflict-free ds_read_b128, standard MFMA math.
// OUTMODE 0: f32 store | 2: f32 += | 4: fused QKV(+RoPE) | 6: interleaved silu-gate
template <int TN, int OUTMODE>
__global__ __launch_bounds__(256) void k_gemm2(const bf16_t* __restrict__ A,
                                               const bf16_t* __restrict__ Bt,
                                               float* __restrict__ Cf,
                                               bf16_t* __restrict__ Cb,
                                               bf16_t* __restrict__ aux1,
                                               bf16_t* __restrict__ aux2,
                                               const float* __restrict__ ct,
                                               const float* __restrict__ st,
                                               int M, int N, int K) {
  constexpr int JN = TN / 32;            // B frags per wave
  constexpr int NBI = TN / 32;           // B stage issues (rows/32)
  __shared__ bf16_t As[128 * 64];
  __shared__ bf16_t Bs[TN * 64];
  const int t = threadIdx.x;
  const int w = t >> 6, l = t & 63;
  const int h = l >> 4, r16 = l & 15;
  const int m0 = blockIdx.y * 128, n0 = blockIdx.x * TN;
  const int wr = (w >> 1) * 64;
  const int wc = (w & 1) * (TN / 2);
  // staging geometry: per issue a wave covers 8 rows x 64 k
  const int sr8  = l >> 3;               // 0..7 row within wave-slab
  const int xch  = ((l & 7) ^ sr8) * 8;  // pre-swizzled k-chunk offset (elems)
  const int s7   = r16 & 7;              // reader swizzle key

  f32x4 acc[4][JN] = {};

  const bf16_t* pa = &A[(size_t)(m0 + w * 8 + sr8) * K + xch];
  const bf16_t* pb = &Bt[(size_t)(n0 + w * 8 + sr8) * K + xch];

  for (int k0 = 0; k0 < K; k0 += 64) {
#pragma unroll
    for (int i = 0; i < 4; ++i)
      gll16(pa + (size_t)i * 32 * K + k0, &As[(i * 32 + w * 8) * 64]);
#pragma unroll
    for (int i = 0; i < NBI; ++i)
      gll16(pb + (size_t)i * 32 * K + k0, &Bs[(i * 32 + w * 8) * 64]);
    __syncthreads();
#pragma unroll
    for (int kk = 0; kk < 2; ++kk) {
      const int p = ((kk * 4 + h) ^ s7) * 8;   // swizzled read position (elems)
      bf16x8 af[4], bfr[JN];
#pragma unroll
      for (int i = 0; i < 4; ++i)
        af[i] = *(const bf16x8*)&As[(wr + i * 16 + r16) * 64 + p];
#pragma unroll
      for (int j = 0; j < JN; ++j)
        bfr[j] = *(const bf16x8*)&Bs[(wc + j * 16 + r16) * 64 + p];
#pragma unroll
      for (int i = 0; i < 4; ++i)
#pragma unroll
        for (int j = 0; j < JN; ++j)
          acc[i][j] = __builtin_amdgcn_mfma_f32_16x16x32_bf16(af[i], bfr[j], acc[i][j], 0, 0, 0);
    }
    __syncthreads();
  }

  if constexpr (OUTMODE == 4) {
    // fused QKV epilogue: region by n0 (0..1023 q, 1024..2047 k, 2048..3071 v)
    const int reg = n0 >> 10;
    const int cbase = (n0 & 1023) + wc;
    if (reg == 2) {
#pragma unroll
      for (int i = 0; i < 4; ++i)
#pragma unroll
        for (int j = 0; j < JN; ++j)
#pragma unroll
          for (int r = 0; r < 4; ++r) {
            int row = m0 + wr + i * 16 + h * 4 + r;
            Cb[(size_t)row * DIM + cbase + j * 16 + r16] = (bf16_t)acc[i][j][r];
          }
    } else {
      bf16_t* dst = reg ? aux2 : aux1;
#pragma unroll
      for (int i = 0; i < 4; ++i)
#pragma unroll
        for (int r = 0; r < 4; ++r) {
          int row = m0 + wr + i * 16 + h * 4 + r;
          float c0 = ct[row * 32 + r16],      s0 = st[row * 32 + r16];
          float c1 = ct[row * 32 + 16 + r16], s1 = st[row * 32 + 16 + r16];
          float lo0 = acc[i][0][r], hi0 = acc[i][2][r];
          float lo1 = acc[i][1][r], hi1 = acc[i][3][r];
          size_t rb = (size_t)row * DIM + cbase;
          dst[rb + r16]      = (bf16_t)(lo0 * c0 - hi0 * s0);
          dst[rb + 32 + r16] = (bf16_t)(hi0 * c0 + lo0 * s0);
          dst[rb + 16 + r16] = (bf16_t)(lo1 * c1 - hi1 * s1);
          dst[rb + 48 + r16] = (bf16_t)(hi1 * c1 + lo1 * s1);
        }
    }
  } else if constexpr (OUTMODE == 6) {
    // interleaved w1/w3 -> fused silu-gate. j even = w1, j odd = w3 (same features).
    const int fbase = ((n0 + wc) >> 5) * 16;
#pragma unroll
    for (int i = 0; i < 4; ++i)
#pragma unroll
      for (int r = 0; r < 4; ++r) {
        int row = m0 + wr + i * 16 + h * 4 + r;
        float a0 = acc[i][0][r], b0 = acc[i][1][r];
        float a1 = acc[i][2][r], b1 = acc[i][3][r];
        float g0 = a0 / (1.f + expf(-a0)) * b0;
        float g1v = a1 / (1.f + expf(-a1)) * b1;
        size_t rb = (size_t)row * FF + fbase;
        aux1[rb + r16]      = (bf16_t)g0;
        aux1[rb + 16 + r16] = (bf16_t)g1v;
      }
  } else {
#pragma unroll
    for (int i = 0; i < 4; ++i)
#pragma unroll
      for (int j = 0; j < JN; ++j)
#pragma unroll
        for (int r = 0; r < 4; ++r) {
          int row = m0 + wr + i * 16 + h * 4 + r;
          int col = n0 + wc + j * 16 + r16;
          if (col < N) {
            float vv = acc[i][j][r];
            size_t idx = (size_t)row * N + col;
            if (OUTMODE == 0) Cf[idx] = vv;
            else Cf[idx] += vv;
          }
        }
  }
}

// ------- flash attention: 4 waves/block, swapped-QK layout, causal-paired -------
__global__ __launch_bounds__(256) void k_attn4(const bf16_t* __restrict__ qb,
                                               const bf16_t* __restrict__ kb,
                                               const bf16_t* __restrict__ vb,
                                               bf16_t* __restrict__ ao) {
  __shared__ bf16_t Ks[64][72];       // K chunk: [key][dh]
  __shared__ bf16_t Vt[64][72];       // V chunk transposed: [dh][key]
  __shared__ bf16_t Pl[4][16][72];    // per-wave P: [qrow][key]
  const int pq = blockIdx.x;          // 0..15
  const int head = blockIdx.y;
  const int t = threadIdx.x;
  const int w = t >> 6, l = t & 63;
  const int h = l >> 4, r16 = l & 15;
  const size_t hoff = (size_t)head * HD;
  const int srow = t >> 2;            // 0..63 staging row
  const int ssg  = (t & 3) * 8;       // 0,8,16,24

#pragma unroll
  for (int half = 0; half < 2; ++half) {
    const int qt = half ? (31 - pq) : pq;
    const int q0 = qt * 64 + w * 16;    // this wave's first q row
    const int q_abs = q0 + r16;         // this lane's q row (softmax axis)

    bf16x8 aq[2];
#pragma unroll
    for (int c = 0; c < 2; ++c)
      aq[c] = *(const bf16x8*)&qb[(size_t)(q0 + r16) * DIM + hoff + c * 32 + h * 8];

    f32x4 o[4] = {};
    float mrun = -1e30f, lrun = 0.f;

    const int kend = qt * 64 + 63;
    for (int k0 = 0; k0 <= kend; k0 += 64) {
      // ---- cooperative stage: K direct, V transposed ----
#pragma unroll
      for (int it = 0; it < 2; ++it) {
        bf16x8 kv = *(const bf16x8*)&kb[(size_t)(k0 + srow) * DIM + hoff + ssg + it * 32];
        *(bf16x8*)&Ks[srow][ssg + it * 32] = kv;
      }
#pragma unroll
      for (int it = 0; it < 2; ++it) {
        bf16x8 vv = *(const bf16x8*)&vb[(size_t)(k0 + srow) * DIM + hoff + ssg + it * 32];
#pragma unroll
        for (int j = 0; j < 8; ++j) Vt[ssg + it * 32 + j][srow] = vv[j];
      }
      __syncthreads();

      if (k0 <= q0 + 15) {              // wave-uniform: skip fully-masked chunks
        // ---- scores transposed: D[key][q] ----
        f32x4 sc[4];
        __builtin_amdgcn_s_setprio(1);
#pragma unroll
        for (int tc = 0; tc < 4; ++tc) {
          f32x4 z = {};
          bf16x8 a0 = *(const bf16x8*)&Ks[tc * 16 + r16][h * 8];
          bf16x8 a1 = *(const bf16x8*)&Ks[tc * 16 + r16][32 + h * 8];
          z = __builtin_amdgcn_mfma_f32_16x16x32_bf16(a0, aq[0], z, 0, 0, 0);
          z = __builtin_amdgcn_mfma_f32_16x16x32_bf16(a1, aq[1], z, 0, 0, 0);
          sc[tc] = z;
        }
        __builtin_amdgcn_s_setprio(0);
        // ---- mask + scale; per-lane max over 16 keys ----
        float pmax = -1e30f;
#pragma unroll
        for (int tc = 0; tc < 4; ++tc)
#pragma unroll
          for (int r = 0; r < 4; ++r) {
            int key = k0 + tc * 16 + h * 4 + r;
            float v = sc[tc][r] * 0.125f;
            if (key > q_abs) v = -1e30f;
            sc[tc][r] = v;
            pmax = fmaxf(pmax, v);
          }
        pmax = fmaxf(pmax, __shfl_xor(pmax, 16));
        pmax = fmaxf(pmax, __shfl_xor(pmax, 32));
        float mnew = fmaxf(mrun, pmax);
        float alpha = expf(mrun - mnew);
        mrun = mnew;
        float ssum = 0.f;
#pragma unroll
        for (int tc = 0; tc < 4; ++tc)
#pragma unroll
          for (int r = 0; r < 4; ++r) {
            float pv = expf(sc[tc][r] - mnew);
            sc[tc][r] = pv;
            ssum += pv;
          }
        ssum += __shfl_xor(ssum, 16);
        ssum += __shfl_xor(ssum, 32);
        lrun = lrun * alpha + ssum;
        // ---- write P^T to LDS: Pl[q][key] ----
#pragma unroll
        for (int tc = 0; tc < 4; ++tc)
#pragma unroll
          for (int r = 0; r < 4; ++r)
            Pl[w][r16][tc * 16 + h * 4 + r] = (bf16_t)sc[tc][r];
        // ---- rescale o: alpha for o-row q=h*4+r lives in lane h*4+r ----
        float ar[4];
#pragma unroll
        for (int r = 0; r < 4; ++r) ar[r] = __shfl(alpha, h * 4 + r);
#pragma unroll
        for (int cti = 0; cti < 4; ++cti)
#pragma unroll
          for (int r = 0; r < 4; ++r) o[cti][r] *= ar[r];
        // ---- PV ----
        bf16x8 pa0 = *(const bf16x8*)&Pl[w][r16][h * 8];
        bf16x8 pa1 = *(const bf16x8*)&Pl[w][r16][32 + h * 8];
        __builtin_amdgcn_s_setprio(1);
#pragma unroll
        for (int cti = 0; cti < 4; ++cti) {
          bf16x8 v0 = *(const bf16x8*)&Vt[cti * 16 + r16][h * 8];
          bf16x8 v1 = *(const bf16x8*)&Vt[cti * 16 + r16][32 + h * 8];
          o[cti] = __builtin_amdgcn_mfma_f32_16x16x32_bf16(pa0, v0, o[cti], 0, 0, 0);
          o[cti] = __builtin_amdgcn_mfma_f32_16x16x32_bf16(pa1, v1, o[cti], 0, 0, 0);
        }
        __builtin_amdgcn_s_setprio(0);
      }
      __syncthreads();
    }
    float lr[4];
#pragma unroll
    for (int r = 0; r < 4; ++r) lr[r] = __shfl(lrun, h * 4 + r);
#pragma unroll
    for (int cti = 0; cti < 4; ++cti)
#pragma unroll
      for (int r = 0; r < 4; ++r) {
        int row = q0 + h * 4 + r;
        ao[(size_t)row * DIM + hoff + cti * 16 + r16] = (bf16_t)(o[cti][r] / lr[r]);
      }
  }
}

extern "C" void kernel_launch(void* const* d_in, const int* in_sizes, int n_in,
                              void* d_out, int out_size, void* d_ws, size_t ws_size,
                              hipStream_t stream) {
  const int*   ids  = (const int*)d_in[0];
  const float* temb = (const float*)d_in[1];
  const float* Wq   = (const float*)d_in[2];
  const float* Wk   = (const float*)d_in[3];
  const float* Wv   = (const float*)d_in[4];
  const float* Wo   = (const float*)d_in[5];
  const float* ln1s = (const float*)d_in[6];
  const float* ln1b = (const float*)d_in[7];
  const float* ln2s = (const float*)d_in[8];
  const float* ln2b = (const float*)d_in[9];
  const float* w1   = (const float*)d_in[10];
  const float* w2   = (const float*)d_in[11];
  const float* w3   = (const float*)d_in[12];
  const float* lnfs = (const float*)d_in[13];
  const float* lnfb = (const float*)d_in[14];
  const float* lmh  = (const float*)d_in[15];
  float* out = (float*)d_out;

  char* p = (char*)d_ws;
  size_t used = 0;
  auto alloc = [&](size_t bytes) {
    void* r = (void*)p;
    size_t a = (bytes + 255) & ~(size_t)255;
    p += a; used += a;
    return r;
  };
  // activations + tables
  float*  x     = (float*)alloc((size_t)SEQ * DIM * 4);
  bf16_t* hb    = (bf16_t*)alloc((size_t)SEQ * DIM * 2);
  bf16_t* qb2   = (bf16_t*)alloc((size_t)SEQ * DIM * 2);
  bf16_t* kb2   = (bf16_t*)alloc((size_t)SEQ * DIM * 2);
  bf16_t* vb2   = (bf16_t*)alloc((size_t)SEQ * DIM * 2);
  bf16_t* aob   = (bf16_t*)alloc((size_t)SEQ * DIM * 2);
  bf16_t* gateb = (bf16_t*)alloc((size_t)SEQ * FF * 2);
  float*  ctab  = (float*)alloc((size_t)SEQ * 32 * 4);
  float*  stab  = (float*)alloc((size_t)SEQ * 32 * 4);

  const size_t szDD = (size_t)DIM * DIM;    // 1M elems
  const size_t szDF = (size_t)DIM * FF;     // 4M elems
  const size_t wt_bytes = ((size_t)NL * (3 * szDD + szDD + 2 * szDF + szDF) + (size_t)VOCP * DIM) * 2;
  const bool bigws = (ws_size >= used + wt_bytes + (1u << 20));

  bf16_t *bQKV, *bWo, *bW13, *bw2, *blm, *wscratch = nullptr;
  if (bigws) {
    bQKV = (bf16_t*)alloc(NL * 3 * szDD * 2);
    bWo  = (bf16_t*)alloc(NL * szDD * 2);
    bW13 = (bf16_t*)alloc(NL * 2 * szDF * 2);
    bw2  = (bf16_t*)alloc(NL * szDF * 2);
    blm  = (bf16_t*)alloc((size_t)VOCP * DIM * 2);
  } else {
    wscratch = (bf16_t*)alloc(2 * szDF * 2);   // enough for fused w13 of one layer
    bQKV = bWo = bW13 = bw2 = blm = wscratch;
  }

  auto cvt = [&](const float* src, bf16_t* dst, int K_, int N_, int Npad_, int nz,
                 size_t dstride, int imode) {
    dim3 g(Npad_ / 64, K_ / 64, nz);
    k_cvt_t<<<g, 256, 0, stream>>>(src, dst, K_, N_, Npad_, dstride, imode);
  };

  if (bigws) {
    cvt(Wq, bQKV,             DIM, DIM, DIM, NL, 3 * szDD, 0);
    cvt(Wk, bQKV + szDD,      DIM, DIM, DIM, NL, 3 * szDD, 0);
    cvt(Wv, bQKV + 2 * szDD,  DIM, DIM, DIM, NL, 3 * szDD, 0);
    cvt(Wo, bWo,              DIM, DIM, DIM, NL, szDD, 0);
    cvt(w1, bW13,             DIM, FF,  FF,  NL, 2 * szDF, 1);   // interleaved even
    cvt(w3, bW13,             DIM, FF,  FF,  NL, 2 * szDF, 2);   // interleaved odd
    cvt(w2, bw2,              FF,  DIM, DIM, NL, szDF, 0);
    cvt(lmh, blm,             DIM, VOC, VOCP, 1, 0, 0);
  }
  auto wpQKV = [&](int lyr) -> bf16_t* {
    if (bigws) return bQKV + (size_t)lyr * 3 * szDD;
    cvt(Wq + (size_t)lyr * szDD, wscratch,            DIM, DIM, DIM, 1, 0, 0);
    cvt(Wk + (size_t)lyr * szDD, wscratch + szDD,     DIM, DIM, DIM, 1, 0, 0);
    cvt(Wv + (size_t)lyr * szDD, wscratch + 2 * szDD, DIM, DIM, DIM, 1, 0, 0);
    return wscratch;
  };
  auto wpW13 = [&](int lyr) -> bf16_t* {
    if (bigws) return bW13 + (size_t)lyr * 2 * szDF;
    cvt(w1 + (size_t)lyr * szDF, wscratch, DIM, FF, FF, 1, 0, 1);
    cvt(w3 + (size_t)lyr * szDF, wscratch, DIM, FF, FF, 1, 0, 2);
    return wscratch;
  };
  auto wp1 = [&](bf16_t* big, const float* src, int lyr, int K_, int N_, int Npad_) -> bf16_t* {
    if (bigws) return big + (size_t)lyr * Npad_ * K_;
    cvt(src + (size_t)lyr * K_ * N_, wscratch, K_, N_, Npad_, 1, 0, 0);
    return wscratch;
  };

  k_rtab<<<(SEQ * 32) / 256, 256, 0, stream>>>(ctab, stab);
  k_embed<<<SEQ, 256, 0, stream>>>(ids, temb, x);

  dim3 gQKV(3 * DIM / 128, SEQ / 128);   // 24 x 16 = 384
  dim3 gDD(DIM / 64, SEQ / 128);         // 16 x 16 = 256
  dim3 gW13(2 * FF / 128, SEQ / 128);    // 64 x 16 = 1024
  dim3 gLM(VOCP / 64, SEQ / 128);        // 22 x 16 = 352
  dim3 gAt(SEQ / 128, NH);               // 16 pairs x 16 heads = 256

  for (int l = 0; l < NL; ++l) {
    k_ln<<<SEQ / 4, 256, 0, stream>>>(x, ln1s + (size_t)l * DIM, ln1b + (size_t)l * DIM, hb);
    k_gemm2<128, 4><<<gQKV, 256, 0, stream>>>(hb, wpQKV(l), nullptr, vb2, qb2, kb2,
                                              ctab, stab, SEQ, 3 * DIM, DIM);
    k_attn4<<<gAt, 256, 0, stream>>>(qb2, kb2, vb2, aob);
    k_gemm2<64, 2><<<gDD, 256, 0, stream>>>(aob, wp1(bWo, Wo, l, DIM, DIM, DIM), x, nullptr,
                                            nullptr, nullptr, nullptr, nullptr, SEQ, DIM, DIM);
    k_ln<<<SEQ / 4, 256, 0, stream>>>(x, ln2s + (size_t)l * DIM, ln2b + (size_t)l * DIM, hb);
    k_gemm2<128, 6><<<gW13, 256, 0, stream>>>(hb, wpW13(l), nullptr, nullptr, gateb, nullptr,
                                              nullptr, nullptr, SEQ, 2 * FF, DIM);
    k_gemm2<64, 2><<<gDD, 256, 0, stream>>>(gateb, wp1(bw2, w2, l, FF, DIM, DIM), x, nullptr,
                                            nullptr, nullptr, nullptr, nullptr, SEQ, DIM, FF);
  }
  k_ln<<<SEQ / 4, 256, 0, stream>>>(x, lnfs, lnfb, hb);
  k_gemm2<64, 0><<<gLM, 256, 0, stream>>>(hb, bigws ? blm : wp1(blm, lmh, 0, DIM, VOC, VOCP),
                                          out, nullptr, nullptr, nullptr, nullptr, nullptr,
                                          SEQ, VOC, DIM);
}